// Round 15
// baseline (857.630 us; speedup 1.0000x reference)
//
#include <hip/hip_runtime.h>
#include <hip/hip_bf16.h>
#include <hip/hip_fp16.h>

#define NLAYERS 4
#define GRID_STRIDE 2048

typedef _Float16 half8_t __attribute__((ext_vector_type(8)));
typedef float float4_t __attribute__((ext_vector_type(4)));

// ---------------- small zero kernel ----------------
__global__ void zero_ints(int* __restrict__ p, int n)
{
    int i = blockIdx.x * 256 + threadIdx.x;
    if (i < n) p[i] = 0;
}

// ---------------- CSR build ----------------
__global__ void hist_kernel(const int* __restrict__ dsts, int* __restrict__ counts, int E)
{
    int i = blockIdx.x * 256 + threadIdx.x;
    if (i < E) atomicAdd(&counts[dsts[i]], 1);
}

__global__ __launch_bounds__(256) void scan1(const int* __restrict__ counts,
                                             int* __restrict__ offsets,
                                             int* __restrict__ blocksums, int N)
{
    __shared__ int sdata[256];
    int t = threadIdx.x;
    int bbase = blockIdx.x * 1024;
    int v[4]; int s = 0;
#pragma unroll
    for (int q = 0; q < 4; q++) {
        int idx = bbase + t * 4 + q;
        v[q] = (idx < N) ? counts[idx] : 0;
        s += v[q];
    }
    sdata[t] = s;
    __syncthreads();
    for (int off = 1; off < 256; off <<= 1) {
        int x = (t >= off) ? sdata[t - off] : 0;
        __syncthreads();
        sdata[t] += x;
        __syncthreads();
    }
    int excl = sdata[t] - s;
    int run = excl;
#pragma unroll
    for (int q = 0; q < 4; q++) {
        int idx = bbase + t * 4 + q;
        if (idx < N) offsets[idx] = run;
        run += v[q];
    }
    if (t == 255) blocksums[blockIdx.x] = sdata[255];
}

__global__ void scan2(int* __restrict__ blocksums, int nb)
{
    if (threadIdx.x == 0 && blockIdx.x == 0) {
        int run = 0;
        for (int b = 0; b < nb; b++) { int t = blocksums[b]; blocksums[b] = run; run += t; }
    }
}

__global__ void scan3(int* __restrict__ offsets, const int* __restrict__ blocksums,
                      int* __restrict__ cursor, int N)
{
    int i = blockIdx.x * 256 + threadIdx.x;
    if (i < N) {
        int v = offsets[i] + blocksums[i >> 10];
        offsets[i] = v;
        cursor[i] = v;
    }
}

// scatter only perm (1 random 4B stream instead of 3)
__global__ void scatter_perm(const int* __restrict__ dsts, int* __restrict__ cursor,
                             int* __restrict__ perm, int E)
{
    int i = blockIdx.x * 256 + threadIdx.x;
    if (i < E) {
        int slot = atomicAdd(&cursor[dsts[i]], 1);
        perm[slot] = i;
    }
}

// coalesced writes, cache-resident random reads
__global__ void gather_sd(const int* __restrict__ perm, const int* __restrict__ srcs,
                          const int* __restrict__ dsts, int* __restrict__ srcp,
                          int* __restrict__ dstp, int E)
{
    int i = blockIdx.x * 256 + threadIdx.x;
    if (i < E) {
        int e = perm[i];
        srcp[i] = srcs[e];
        dstp[i] = dsts[e];
    }
}

// ---------------- init projections ----------------
__global__ void init_proj4(const float* __restrict__ in, const float* __restrict__ w,
                           const float* __restrict__ b, float4* __restrict__ out, size_t n4)
{
    size_t i = (size_t)blockIdx.x * 256 + threadIdx.x;
    if (i < n4) {
        int j4 = (int)(i & 7) * 4;
        float xv = in[i >> 3];
        float4 wv = *(const float4*)(w + j4);
        float4 bv = *(const float4*)(b + j4);
        out[i] = make_float4(fmaf(xv, wv.x, bv.x), fmaf(xv, wv.y, bv.y),
                             fmaf(xv, wv.z, bv.z), fmaf(xv, wv.w, bv.w));
    }
}

__global__ void init_ep16(const float* __restrict__ e_in, const int* __restrict__ perm,
                          const float* __restrict__ w, const float* __restrict__ b,
                          __half2* __restrict__ out, size_t n4)
{
    size_t i = (size_t)blockIdx.x * 256 + threadIdx.x;
    if (i < n4) {
        int row = (int)(i >> 3);
        float xv = e_in[perm[row]];
        int j4 = (int)(i & 7) * 4;
        float4 wv = *(const float4*)(w + j4);
        float4 bv = *(const float4*)(b + j4);
        out[i * 2]     = __floats2half2_rn(fmaf(xv, wv.x, bv.x), fmaf(xv, wv.y, bv.y));
        out[i * 2 + 1] = __floats2half2_rn(fmaf(xv, wv.z, bv.z), fmaf(xv, wv.w, bv.w));
    }
}

// ---------------- node GEMMs: one node per thread, scalar-broadcast weights ----------------
__device__ __forceinline__ void mat32(const float* __restrict__ hrow,
                                      const float* __restrict__ W, const float* __restrict__ Wb,
                                      float* __restrict__ dst)
{
    float acc[32];
#pragma unroll
    for (int j = 0; j < 32; j++) acc[j] = Wb[j];
#pragma unroll 4
    for (int k = 0; k < 32; k++) {
        float hk = hrow[k];
#pragma unroll
        for (int j = 0; j < 32; j++) acc[j] = fmaf(hk, W[k * 32 + j], acc[j]);
    }
    float4* o = (float4*)dst;
#pragma unroll
    for (int q = 0; q < 8; q++) o[q] = make_float4(acc[4*q], acc[4*q+1], acc[4*q+2], acc[4*q+3]);
}

__device__ __forceinline__ void mat32h(const float* __restrict__ hrow,
                                       const float* __restrict__ W, const float* __restrict__ Wb,
                                       __half* __restrict__ dst)
{
    float acc[32];
#pragma unroll
    for (int j = 0; j < 32; j++) acc[j] = Wb[j];
#pragma unroll 4
    for (int k = 0; k < 32; k++) {
        float hk = hrow[k];
#pragma unroll
        for (int j = 0; j < 32; j++) acc[j] = fmaf(hk, W[k * 32 + j], acc[j]);
    }
    __half2* o = (__half2*)dst;
#pragma unroll
    for (int q = 0; q < 16; q++) o[q] = __floats2half2_rn(acc[2*q], acc[2*q+1]);
}

__global__ __launch_bounds__(64) void node_gemm(
    const float* __restrict__ h,
    const float* __restrict__ Aw, const float* __restrict__ Ab,
    const float* __restrict__ Bw, const float* __restrict__ Bb,
    const float* __restrict__ Uw, const float* __restrict__ Ub,
    const float* __restrict__ Vw, const float* __restrict__ Vb,
    __half* __restrict__ Ahh, __half* __restrict__ Bhh,
    float* __restrict__ Uhh, __half* __restrict__ Vhh, int N)
{
    int nid = blockIdx.x * 64 + threadIdx.x;
    if (nid >= N) return;
    const float* hrow = h + (size_t)nid * 32;
    size_t o = (size_t)nid * 32;
    mat32h(hrow, Aw, Ab, Ahh + o);
    mat32h(hrow, Bw, Bb, Bhh + o);
    mat32(hrow, Uw, Ub, Uhh + o);   // Uhh == hnew (folded)
    mat32h(hrow, Vw, Vb, Vhh + o);
}

// ---- phase A (MFMA): en = e @ Cw + Cb + Ah[dst] + Bh[src] for 16-edge tiles per wave ----
__global__ __launch_bounds__(256) void edge_en(
    const __half* __restrict__ ep,
    const int* __restrict__ srcp, const int* __restrict__ dstp,
    const __half* __restrict__ Ah, const __half* __restrict__ Bh,
    const float* __restrict__ Cw, const float* __restrict__ Cb,
    __half* __restrict__ enh, float* __restrict__ partial, int E)
{
    __shared__ float red[256];
    int tid = threadIdx.x;
    int lane = tid & 63;
    int m = lane & 15, q = lane >> 4;         // q in 0..3
    half8_t b0, b1;
#pragma unroll
    for (int i = 0; i < 8; i++) {
        int k = q * 8 + i;
        b0[i] = (_Float16)Cw[k * 32 + m];
        b1[i] = (_Float16)Cw[k * 32 + m + 16];
    }
    float cb0 = Cb[m], cb1 = Cb[m + 16];
    float es0 = 0.f, eq0 = 0.f, es1 = 0.f, eq1 = 0.f;

    int ntile = (E + 15) >> 4;
    int wid = blockIdx.x * 4 + (tid >> 6);
    int nwave = gridDim.x * 4;
    for (int t = wid; t < ntile; t += nwave) {
        int base = t << 4;
        int arow = base + m;
        if (arow >= E) arow = E - 1;
        half8_t a = *(const half8_t*)(ep + (size_t)arow * 32 + q * 8);
        float4_t acc0 = __builtin_amdgcn_mfma_f32_16x16x32_f16(a, b0, (float4_t){0.f,0.f,0.f,0.f}, 0, 0, 0);
        float4_t acc1 = __builtin_amdgcn_mfma_f32_16x16x32_f16(a, b1, (float4_t){0.f,0.f,0.f,0.f}, 0, 0, 0);
#pragma unroll
        for (int reg = 0; reg < 4; reg++) {
            int row = q * 4 + reg;
            int edge = base + row;
            if (edge < E) {
                int s = srcp[edge], d = dstp[edge];
                float ah0 = __half2float(Ah[(size_t)d * 32 + m]);
                float bh0 = __half2float(Bh[(size_t)s * 32 + m]);
                float ah1 = __half2float(Ah[(size_t)d * 32 + m + 16]);
                float bh1 = __half2float(Bh[(size_t)s * 32 + m + 16]);
                float en0 = acc0[reg] + cb0 + ah0 + bh0;
                float en1 = acc1[reg] + cb1 + ah1 + bh1;
                enh[(size_t)edge * 32 + m]      = __float2half_rn(en0);
                enh[(size_t)edge * 32 + m + 16] = __float2half_rn(en1);
                es0 += en0; eq0 += en0 * en0;
                es1 += en1; eq1 += en1 * en1;
            }
        }
    }
    float* p = partial + (size_t)blockIdx.x * 64;
    __syncthreads();
    red[tid] = es0;
    __syncthreads();
    if (tid < 16) {
        float s = 0.f;
#pragma unroll
        for (int w = 0; w < 4; w++)
#pragma unroll
            for (int k = 0; k < 4; k++) s += red[w * 64 + k * 16 + tid];
        p[tid] = s;
    }
    __syncthreads();
    red[tid] = es1;
    __syncthreads();
    if (tid < 16) {
        float s = 0.f;
#pragma unroll
        for (int w = 0; w < 4; w++)
#pragma unroll
            for (int k = 0; k < 4; k++) s += red[w * 64 + k * 16 + tid];
        p[16 + tid] = s;
    }
    __syncthreads();
    red[tid] = eq0;
    __syncthreads();
    if (tid < 16) {
        float s = 0.f;
#pragma unroll
        for (int w = 0; w < 4; w++)
#pragma unroll
            for (int k = 0; k < 4; k++) s += red[w * 64 + k * 16 + tid];
        p[32 + tid] = s;
    }
    __syncthreads();
    red[tid] = eq1;
    __syncthreads();
    if (tid < 16) {
        float s = 0.f;
#pragma unroll
        for (int w = 0; w < 4; w++)
#pragma unroll
            for (int k = 0; k < 4; k++) s += red[w * 64 + k * 16 + tid];
        p[48 + tid] = s;
    }
}

// ---- phase B: CSR walk; sigmoid + Vh gather; fused e-apply (ep += relu(en*sc+sh)); ILP4 ----
__global__ __launch_bounds__(256) void node_agg(
    const __half* __restrict__ enh, const int* __restrict__ srcp,
    const int* __restrict__ offsets, const int* __restrict__ counts,
    const __half* __restrict__ Vh, float* __restrict__ hnew,
    __half* __restrict__ ep, const float* __restrict__ sc_e, const float* __restrict__ sh_e,
    float* __restrict__ partial, int N)
{
    __shared__ float red[256];
    int tid = threadIdx.x, j = tid & 31, grp = tid >> 5;
    float sc = sc_e[j], sh = sh_e[j];
    float hsum = 0.f, hsq = 0.f;
    for (int nb0 = blockIdx.x * 8; nb0 < N; nb0 += gridDim.x * 8) {
        int node = nb0 + grp;
        if (node >= N) break;
        int start = offsets[node], len = counts[node];
        float num = 0.f, den = 0.f;
        int qq = 0;
        for (; qq + 4 <= len; qq += 4) {
            int p0 = start + qq, p1 = p0 + 1, p2 = p0 + 2, p3 = p0 + 3;
            int s0 = srcp[p0], s1 = srcp[p1], s2 = srcp[p2], s3 = srcp[p3];
            float en0 = __half2float(enh[(size_t)p0 * 32 + j]);
            float en1 = __half2float(enh[(size_t)p1 * 32 + j]);
            float en2 = __half2float(enh[(size_t)p2 * 32 + j]);
            float en3 = __half2float(enh[(size_t)p3 * 32 + j]);
            float vh0 = __half2float(Vh[(size_t)s0 * 32 + j]);
            float vh1 = __half2float(Vh[(size_t)s1 * 32 + j]);
            float vh2 = __half2float(Vh[(size_t)s2 * 32 + j]);
            float vh3 = __half2float(Vh[(size_t)s3 * 32 + j]);
            float e0 = __half2float(ep[(size_t)p0 * 32 + j]);
            float e1 = __half2float(ep[(size_t)p1 * 32 + j]);
            float e2 = __half2float(ep[(size_t)p2 * 32 + j]);
            float e3 = __half2float(ep[(size_t)p3 * 32 + j]);
            float sg0 = 1.f / (1.f + __expf(-en0));
            float sg1 = 1.f / (1.f + __expf(-en1));
            float sg2 = 1.f / (1.f + __expf(-en2));
            float sg3 = 1.f / (1.f + __expf(-en3));
            num = fmaf(sg0, vh0, num); num = fmaf(sg1, vh1, num);
            num = fmaf(sg2, vh2, num); num = fmaf(sg3, vh3, num);
            den += (sg0 + sg1) + (sg2 + sg3);
            ep[(size_t)p0 * 32 + j] = __float2half_rn(e0 + fmaxf(fmaf(en0, sc, sh), 0.f));
            ep[(size_t)p1 * 32 + j] = __float2half_rn(e1 + fmaxf(fmaf(en1, sc, sh), 0.f));
            ep[(size_t)p2 * 32 + j] = __float2half_rn(e2 + fmaxf(fmaf(en2, sc, sh), 0.f));
            ep[(size_t)p3 * 32 + j] = __float2half_rn(e3 + fmaxf(fmaf(en3, sc, sh), 0.f));
        }
        for (; qq < len; qq++) {
            int p0 = start + qq;
            int s0 = srcp[p0];
            float en0 = __half2float(enh[(size_t)p0 * 32 + j]);
            float vh0 = __half2float(Vh[(size_t)s0 * 32 + j]);
            float e0 = __half2float(ep[(size_t)p0 * 32 + j]);
            float sg0 = 1.f / (1.f + __expf(-en0));
            num = fmaf(sg0, vh0, num);
            den += sg0;
            ep[(size_t)p0 * 32 + j] = __float2half_rn(e0 + fmaxf(fmaf(en0, sc, sh), 0.f));
        }
        size_t ho = (size_t)node * 32 + j;
        float hv = hnew[ho] + num / (den + 1e-6f);   // hnew holds Uh
        hnew[ho] = hv;
        hsum += hv; hsq += hv * hv;
    }
    __syncthreads();
    red[tid] = hsum;
    __syncthreads();
    float hS = 0.f;
    if (tid < 32) {
#pragma unroll
        for (int r = 0; r < 8; r++) hS += red[r * 32 + tid];
    }
    __syncthreads();
    red[tid] = hsq;
    __syncthreads();
    if (tid < 32) {
        float hQ = 0.f;
#pragma unroll
        for (int r = 0; r < 8; r++) hQ += red[r * 32 + tid];
        float* p = partial + (size_t)blockIdx.x * 64;
        p[tid] = hS; p[32 + tid] = hQ;
    }
}

// ---------------- finalize BN stats for one side: 32 blocks, one per feature ----------------
__global__ __launch_bounds__(256) void stats_side(
    const float* __restrict__ partial, int nrows, double cnt,
    const float* __restrict__ g, const float* __restrict__ b,
    float* __restrict__ sc_out, float* __restrict__ sh_out)
{
    int j = blockIdx.x;
    __shared__ double rs[256], rq[256];
    double s = 0.0, q = 0.0;
    for (int r = threadIdx.x; r < nrows; r += 256) {
        s += (double)partial[(size_t)r * 64 + j];
        q += (double)partial[(size_t)r * 64 + 32 + j];
    }
    rs[threadIdx.x] = s; rq[threadIdx.x] = q;
    __syncthreads();
    for (int off = 128; off; off >>= 1) {
        if (threadIdx.x < off) { rs[threadIdx.x] += rs[threadIdx.x + off]; rq[threadIdx.x] += rq[threadIdx.x + off]; }
        __syncthreads();
    }
    if (threadIdx.x == 0) {
        double mean = rs[0] / cnt;
        double var = rq[0] / cnt - mean * mean;
        float scale = g[j] * (float)(1.0 / sqrt(var + 1e-5));
        sc_out[j] = scale;
        sh_out[j] = b[j] - (float)mean * scale;
    }
}

// ---------------- apply (float4): acc += relu(pre*scale + shift) ----------------
__global__ void apply4(const float4* __restrict__ pre, const float* __restrict__ scale,
                       const float* __restrict__ shift, float4* __restrict__ acc, size_t n4)
{
    size_t i = (size_t)blockIdx.x * 256 + threadIdx.x;
    if (i < n4) {
        int j4 = (int)(i & 7) * 4;
        float4 sc = *(const float4*)(scale + j4);
        float4 sh = *(const float4*)(shift + j4);
        float4 p = pre[i], a = acc[i];
        a.x += fmaxf(fmaf(p.x, sc.x, sh.x), 0.f);
        a.y += fmaxf(fmaf(p.y, sc.y, sh.y), 0.f);
        a.z += fmaxf(fmaf(p.z, sc.z, sh.z), 0.f);
        a.w += fmaxf(fmaf(p.w, sc.w, sh.w), 0.f);
        acc[i] = a;
    }
}

// ---- final h apply: h16 = fp16(h + relu(hnew*sc+sh)) into a separate buffer ----
__global__ void apply4_h16(const float4* __restrict__ pre, const float* __restrict__ scale,
                           const float* __restrict__ shift, const float4* __restrict__ hold,
                           __half2* __restrict__ h16, size_t n4)
{
    size_t i = (size_t)blockIdx.x * 256 + threadIdx.x;
    if (i < n4) {
        int j4 = (int)(i & 7) * 4;
        float4 sc = *(const float4*)(scale + j4);
        float4 sh = *(const float4*)(shift + j4);
        float4 p = pre[i], a = hold[i];
        a.x += fmaxf(fmaf(p.x, sc.x, sh.x), 0.f);
        a.y += fmaxf(fmaf(p.y, sc.y, sh.y), 0.f);
        a.z += fmaxf(fmaf(p.z, sc.z, sh.z), 0.f);
        a.w += fmaxf(fmaf(p.w, sc.w, sh.w), 0.f);
        h16[i * 2]     = __floats2half2_rn(a.x, a.y);
        h16[i * 2 + 1] = __floats2half2_rn(a.z, a.w);
    }
}

// ---- predictor (MFMA): [16-edge tile × 96] @ [96 × 32], W1/W2 epilogue, perm scatter ----
__global__ __launch_bounds__(256) void predictor(
    const __half* __restrict__ h16, const __half* __restrict__ e16,
    const int* __restrict__ srcp, const int* __restrict__ dstp, const int* __restrict__ perm,
    const float* __restrict__ W1, const float* __restrict__ b1,
    const float* __restrict__ W2, const float* __restrict__ b2v,
    float* __restrict__ out, int E)
{
    int tid = threadIdx.x;
    int lane = tid & 63;
    int m = lane & 15, q = lane >> 4;
    half8_t bf00, bf01, bf10, bf11, bf20, bf21;
#pragma unroll
    for (int i = 0; i < 8; i++) {
        int k = q * 8 + i;
        bf00[i] = (_Float16)W1[k * 32 + m];
        bf01[i] = (_Float16)W1[k * 32 + m + 16];
        bf10[i] = (_Float16)W1[(32 + k) * 32 + m];
        bf11[i] = (_Float16)W1[(32 + k) * 32 + m + 16];
        bf20[i] = (_Float16)W1[(64 + k) * 32 + m];
        bf21[i] = (_Float16)W1[(64 + k) * 32 + m + 16];
    }
    float b10 = b1[m], b11 = b1[m + 16];
    float w20 = W2[m], w21 = W2[m + 16];
    float b2 = b2v[0];

    int ntile = (E + 15) >> 4;
    int wid = blockIdx.x * 4 + (tid >> 6);
    int nwave = gridDim.x * 4;
    for (int t = wid; t < ntile; t += nwave) {
        int base = t << 4;
        int arow = base + m;
        if (arow >= E) arow = E - 1;
        int s = srcp[arow], d = dstp[arow];
        half8_t a0 = *(const half8_t*)(h16 + (size_t)s * 32 + q * 8);
        half8_t a1 = *(const half8_t*)(h16 + (size_t)d * 32 + q * 8);
        half8_t a2 = *(const half8_t*)(e16 + (size_t)arow * 32 + q * 8);
        float4_t acc0 = {0.f, 0.f, 0.f, 0.f}, acc1 = {0.f, 0.f, 0.f, 0.f};
        acc0 = __builtin_amdgcn_mfma_f32_16x16x32_f16(a0, bf00, acc0, 0, 0, 0);
        acc1 = __builtin_amdgcn_mfma_f32_16x16x32_f16(a0, bf01, acc1, 0, 0, 0);
        acc0 = __builtin_amdgcn_mfma_f32_16x16x32_f16(a1, bf10, acc0, 0, 0, 0);
        acc1 = __builtin_amdgcn_mfma_f32_16x16x32_f16(a1, bf11, acc1, 0, 0, 0);
        acc0 = __builtin_amdgcn_mfma_f32_16x16x32_f16(a2, bf20, acc0, 0, 0, 0);
        acc1 = __builtin_amdgcn_mfma_f32_16x16x32_f16(a2, bf21, acc1, 0, 0, 0);
#pragma unroll
        for (int reg = 0; reg < 4; reg++) {
            float tp = fmaxf(acc0[reg] + b10, 0.f) * w20
                     + fmaxf(acc1[reg] + b11, 0.f) * w21;
            tp += __shfl_xor(tp, 1);
            tp += __shfl_xor(tp, 2);
            tp += __shfl_xor(tp, 4);
            tp += __shfl_xor(tp, 8);
            int edge = base + q * 4 + reg;
            if (m == 0 && edge < E) out[perm[edge]] = tp + b2;
        }
    }
}

extern "C" void kernel_launch(void* const* d_in, const int* in_sizes, int n_in,
                              void* d_out, int out_size, void* d_ws, size_t ws_size,
                              hipStream_t stream)
{
    const int N = in_sizes[0];
    const int E = in_sizes[1];

    const float* x    = (const float*)d_in[0];
    const float* e_in = (const float*)d_in[1];
    const int*   eidx = (const int*)d_in[2];
    const float* pe_w = (const float*)d_in[3];
    const float* pe_b = (const float*)d_in[4];
    const float* ed_w = (const float*)d_in[5];
    const float* ed_b = (const float*)d_in[6];
    const float* Aw = (const float*)d_in[7];
    const float* Ab = (const float*)d_in[8];
    const float* Bw = (const float*)d_in[9];
    const float* Bb = (const float*)d_in[10];
    const float* Cw = (const float*)d_in[11];
    const float* Cb = (const float*)d_in[12];
    const float* Uw = (const float*)d_in[13];
    const float* Ub = (const float*)d_in[14];
    const float* Vw = (const float*)d_in[15];
    const float* Vb = (const float*)d_in[16];
    const float* bn_h_g = (const float*)d_in[17];
    const float* bn_h_b = (const float*)d_in[18];
    const float* bn_e_g = (const float*)d_in[19];
    const float* bn_e_b = (const float*)d_in[20];
    const float* W1w = (const float*)d_in[21];
    const float* W1b = (const float*)d_in[22];
    const float* W2w = (const float*)d_in[23];
    const float* W2b = (const float*)d_in[24];

    const int* srcs = eidx;
    const int* dsts = eidx + E;

    size_t nh = (size_t)N * 32;
    size_t eh = (size_t)E * 32;

    float* ws = (float*)d_ws;
    float* stats     = ws;                            // 128
    float* partial_h = stats + 128;                   // GRID_STRIDE*64
    float* partial_e = partial_h + GRID_STRIDE * 64;  // GRID_STRIDE*64
    float* h    = partial_e + GRID_STRIDE * 64;       // nh floats
    float* hnew = h + nh;                             // nh floats (Uh then h_new)
    __half* Ah  = (__half*)(hnew + nh);               // nh halves (h16 at the end)
    __half* Bh  = Ah + nh;                            // nh halves
    __half* Vh  = Bh + nh;                            // nh halves
    __half* ep  = Vh + nh;                            // eh halves (final e16 at the end)
    __half* enh = ep + eh;                            // eh halves
    int* counts    = (int*)(enh + eh);
    int* offsets   = counts + N;
    int* cursor    = offsets + N;
    int* blocksums = cursor + N;   // 128
    int* perm      = blocksums + 128;
    int* srcp      = perm + E;
    int* dstp      = srcp + E;

    size_t nh4 = nh / 4, eh4 = eh / 4;
    int gh4 = (int)((nh4 + 255) / 256);
    int ge4 = (int)((eh4 + 255) / 256);
    int gN = (N + 255) / 256;
    int gE = (E + 255) / 256;
    int nb = (N + 1023) / 1024;

    // ---- CSR build (dst-sorted edge permutation) ----
    zero_ints<<<gN, 256, 0, stream>>>(counts, N);
    hist_kernel<<<gE, 256, 0, stream>>>(dsts, counts, E);
    scan1<<<nb, 256, 0, stream>>>(counts, offsets, blocksums, N);
    scan2<<<1, 64, 0, stream>>>(blocksums, nb);
    scan3<<<gN, 256, 0, stream>>>(offsets, blocksums, cursor, N);
    scatter_perm<<<gE, 256, 0, stream>>>(dsts, cursor, perm, E);
    gather_sd<<<gE, 256, 0, stream>>>(perm, srcs, dsts, srcp, dstp, E);

    // ---- input projections ----
    init_proj4<<<gh4, 256, 0, stream>>>(x, pe_w, pe_b, (float4*)h, nh4);
    init_ep16<<<ge4, 256, 0, stream>>>(e_in, perm, ed_w, ed_b, (__half2*)ep, eh4);

    for (int l = 0; l < NLAYERS; l++) {
        node_gemm<<<(N + 63) / 64, 64, 0, stream>>>(h,
            Aw + l * 1024, Ab + l * 32,
            Bw + l * 1024, Bb + l * 32,
            Uw + l * 1024, Ub + l * 32,
            Vw + l * 1024, Vb + l * 32,
            Ah, Bh, hnew, Vh, N);
        edge_en<<<GRID_STRIDE, 256, 0, stream>>>(ep, srcp, dstp, Ah, Bh,
            Cw + l * 1024, Cb + l * 32, enh, partial_e, E);
        stats_side<<<32, 256, 0, stream>>>(partial_e, GRID_STRIDE, (double)E,
            bn_e_g + l * 32, bn_e_b + l * 32, stats + 64, stats + 96);
        node_agg<<<GRID_STRIDE, 256, 0, stream>>>(enh, srcp, offsets, counts,
            Vh, hnew, ep, stats + 64, stats + 96, partial_h, N);
        stats_side<<<32, 256, 0, stream>>>(partial_h, GRID_STRIDE, (double)N,
            bn_h_g + l * 32, bn_h_b + l * 32, stats + 0, stats + 32);
        if (l < NLAYERS - 1)
            apply4<<<gh4, 256, 0, stream>>>((const float4*)hnew, stats + 0, stats + 32,
                                            (float4*)h, nh4);
        else
            apply4_h16<<<gh4, 256, 0, stream>>>((const float4*)hnew, stats + 0, stats + 32,
                                                (const float4*)h, (__half2*)Ah, nh4);
    }

    predictor<<<GRID_STRIDE, 256, 0, stream>>>((const __half*)Ah, (const __half*)ep,
                                               srcp, dstp, perm, W1w, W1b, W2w, W2b,
                                               (float*)d_out, E);
}

// Round 16
// 738.647 us; speedup vs baseline: 1.1611x; 1.1611x over previous
//
#include <hip/hip_runtime.h>
#include <hip/hip_bf16.h>
#include <hip/hip_fp16.h>

#define NLAYERS 4
#define GRID_STRIDE 2048

typedef _Float16 half8_t __attribute__((ext_vector_type(8)));
typedef float float4_t __attribute__((ext_vector_type(4)));
typedef float float8_t __attribute__((ext_vector_type(8)));

// ---------------- small zero kernel ----------------
__global__ void zero_ints(int* __restrict__ p, int n)
{
    int i = blockIdx.x * 256 + threadIdx.x;
    if (i < n) p[i] = 0;
}

// ---------------- CSR build ----------------
__global__ void hist_kernel(const int* __restrict__ dsts, int* __restrict__ counts, int E)
{
    int i = blockIdx.x * 256 + threadIdx.x;
    if (i < E) atomicAdd(&counts[dsts[i]], 1);
}

__global__ __launch_bounds__(256) void scan1(const int* __restrict__ counts,
                                             int* __restrict__ offsets,
                                             int* __restrict__ blocksums, int N)
{
    __shared__ int sdata[256];
    int t = threadIdx.x;
    int bbase = blockIdx.x * 1024;
    int v[4]; int s = 0;
#pragma unroll
    for (int q = 0; q < 4; q++) {
        int idx = bbase + t * 4 + q;
        v[q] = (idx < N) ? counts[idx] : 0;
        s += v[q];
    }
    sdata[t] = s;
    __syncthreads();
    for (int off = 1; off < 256; off <<= 1) {
        int x = (t >= off) ? sdata[t - off] : 0;
        __syncthreads();
        sdata[t] += x;
        __syncthreads();
    }
    int excl = sdata[t] - s;
    int run = excl;
#pragma unroll
    for (int q = 0; q < 4; q++) {
        int idx = bbase + t * 4 + q;
        if (idx < N) offsets[idx] = run;
        run += v[q];
    }
    if (t == 255) blocksums[blockIdx.x] = sdata[255];
}

__global__ void scan2(int* __restrict__ blocksums, int nb)
{
    if (threadIdx.x == 0 && blockIdx.x == 0) {
        int run = 0;
        for (int b = 0; b < nb; b++) { int t = blocksums[b]; blocksums[b] = run; run += t; }
    }
}

__global__ void scan3(int* __restrict__ offsets, const int* __restrict__ blocksums,
                      int* __restrict__ cursor, int N)
{
    int i = blockIdx.x * 256 + threadIdx.x;
    if (i < N) {
        int v = offsets[i] + blocksums[i >> 10];
        offsets[i] = v;
        cursor[i] = v;
    }
}

__global__ void scatter_perm(const int* __restrict__ dsts, int* __restrict__ cursor,
                             int* __restrict__ perm, int E)
{
    int i = blockIdx.x * 256 + threadIdx.x;
    if (i < E) {
        int slot = atomicAdd(&cursor[dsts[i]], 1);
        perm[slot] = i;
    }
}

__global__ void gather_sd(const int* __restrict__ perm, const int* __restrict__ srcs,
                          const int* __restrict__ dsts, int* __restrict__ srcp,
                          int* __restrict__ dstp, int E)
{
    int i = blockIdx.x * 256 + threadIdx.x;
    if (i < E) {
        int e = perm[i];
        srcp[i] = srcs[e];
        dstp[i] = dsts[e];
    }
}

// ---------------- init projections ----------------
__global__ void init_proj4(const float* __restrict__ in, const float* __restrict__ w,
                           const float* __restrict__ b, float4* __restrict__ out, size_t n4)
{
    size_t i = (size_t)blockIdx.x * 256 + threadIdx.x;
    if (i < n4) {
        int j4 = (int)(i & 7) * 4;
        float xv = in[i >> 3];
        float4 wv = *(const float4*)(w + j4);
        float4 bv = *(const float4*)(b + j4);
        out[i] = make_float4(fmaf(xv, wv.x, bv.x), fmaf(xv, wv.y, bv.y),
                             fmaf(xv, wv.z, bv.z), fmaf(xv, wv.w, bv.w));
    }
}

__global__ void init_ep16(const float* __restrict__ e_in, const int* __restrict__ perm,
                          const float* __restrict__ w, const float* __restrict__ b,
                          __half2* __restrict__ out, size_t n4)
{
    size_t i = (size_t)blockIdx.x * 256 + threadIdx.x;
    if (i < n4) {
        int row = (int)(i >> 3);
        float xv = e_in[perm[row]];
        int j4 = (int)(i & 7) * 4;
        float4 wv = *(const float4*)(w + j4);
        float4 bv = *(const float4*)(b + j4);
        out[i * 2]     = __floats2half2_rn(fmaf(xv, wv.x, bv.x), fmaf(xv, wv.y, bv.y));
        out[i * 2 + 1] = __floats2half2_rn(fmaf(xv, wv.z, bv.z), fmaf(xv, wv.w, bv.w));
    }
}

// ---- node GEMMs (MFMA): 16-node tile per wave; A=fp16(h row); 4 matrices x 2 col tiles.
// FUSE: during A-load applies prev layer h-update: h += relu(hnew*sc+sh), writes h back.
template <int FUSE>
__global__ __launch_bounds__(256) void node_gemm(
    float* __restrict__ h, const float* __restrict__ hnew_in,
    const float* __restrict__ sc_h, const float* __restrict__ sh_h,
    const float* __restrict__ Aw, const float* __restrict__ Ab,
    const float* __restrict__ Bw, const float* __restrict__ Bb,
    const float* __restrict__ Uw, const float* __restrict__ Ub,
    const float* __restrict__ Vw, const float* __restrict__ Vb,
    __half* __restrict__ Ahh, __half* __restrict__ Bhh,
    float* __restrict__ Uhh, __half* __restrict__ Vhh, int N)
{
    int tid = threadIdx.x;
    int lane = tid & 63;
    int m = lane & 15, q = lane >> 4;
    half8_t bA0, bA1, bB0, bB1, bU0, bU1, bV0, bV1;
    float scq[8], shq[8];
#pragma unroll
    for (int i = 0; i < 8; i++) {
        int k = q * 8 + i;
        bA0[i] = (_Float16)Aw[k * 32 + m];  bA1[i] = (_Float16)Aw[k * 32 + m + 16];
        bB0[i] = (_Float16)Bw[k * 32 + m];  bB1[i] = (_Float16)Bw[k * 32 + m + 16];
        bU0[i] = (_Float16)Uw[k * 32 + m];  bU1[i] = (_Float16)Uw[k * 32 + m + 16];
        bV0[i] = (_Float16)Vw[k * 32 + m];  bV1[i] = (_Float16)Vw[k * 32 + m + 16];
        if (FUSE) { scq[i] = sc_h[k]; shq[i] = sh_h[k]; }
    }
    float ab0 = Ab[m], ab1 = Ab[m + 16];
    float bb0 = Bb[m], bb1 = Bb[m + 16];
    float ub0 = Ub[m], ub1 = Ub[m + 16];
    float vb0 = Vb[m], vb1 = Vb[m + 16];

    int ntile = (N + 15) >> 4;
    int wid = blockIdx.x * 4 + (tid >> 6);
    int nwave = gridDim.x * 4;
    for (int t = wid; t < ntile; t += nwave) {
        int base = t << 4;
        int arow = base + m;
        bool valid = arow < N;
        if (!valid) arow = N - 1;
        float8_t hv = *(const float8_t*)(h + (size_t)arow * 32 + q * 8);
        if (FUSE) {
            float8_t pv = *(const float8_t*)(hnew_in + (size_t)arow * 32 + q * 8);
#pragma unroll
            for (int i = 0; i < 8; i++)
                hv[i] += fmaxf(fmaf(pv[i], scq[i], shq[i]), 0.f);
            if (valid) *(float8_t*)(h + (size_t)arow * 32 + q * 8) = hv;
        }
        half8_t a;
#pragma unroll
        for (int i = 0; i < 8; i++) a[i] = (_Float16)hv[i];
        float4_t aA0 = __builtin_amdgcn_mfma_f32_16x16x32_f16(a, bA0, (float4_t){0,0,0,0}, 0, 0, 0);
        float4_t aA1 = __builtin_amdgcn_mfma_f32_16x16x32_f16(a, bA1, (float4_t){0,0,0,0}, 0, 0, 0);
        float4_t aB0 = __builtin_amdgcn_mfma_f32_16x16x32_f16(a, bB0, (float4_t){0,0,0,0}, 0, 0, 0);
        float4_t aB1 = __builtin_amdgcn_mfma_f32_16x16x32_f16(a, bB1, (float4_t){0,0,0,0}, 0, 0, 0);
        float4_t aU0 = __builtin_amdgcn_mfma_f32_16x16x32_f16(a, bU0, (float4_t){0,0,0,0}, 0, 0, 0);
        float4_t aU1 = __builtin_amdgcn_mfma_f32_16x16x32_f16(a, bU1, (float4_t){0,0,0,0}, 0, 0, 0);
        float4_t aV0 = __builtin_amdgcn_mfma_f32_16x16x32_f16(a, bV0, (float4_t){0,0,0,0}, 0, 0, 0);
        float4_t aV1 = __builtin_amdgcn_mfma_f32_16x16x32_f16(a, bV1, (float4_t){0,0,0,0}, 0, 0, 0);
#pragma unroll
        for (int reg = 0; reg < 4; reg++) {
            int node = base + q * 4 + reg;
            if (node < N) {
                size_t o = (size_t)node * 32;
                Ahh[o + m]      = __float2half_rn(aA0[reg] + ab0);
                Ahh[o + m + 16] = __float2half_rn(aA1[reg] + ab1);
                Bhh[o + m]      = __float2half_rn(aB0[reg] + bb0);
                Bhh[o + m + 16] = __float2half_rn(aB1[reg] + bb1);
                Vhh[o + m]      = __float2half_rn(aV0[reg] + vb0);
                Vhh[o + m + 16] = __float2half_rn(aV1[reg] + vb1);
                Uhh[o + m]      = aU0[reg] + ub0;
                Uhh[o + m + 16] = aU1[reg] + ub1;
            }
        }
    }
}

// ---- phase A (MFMA): en = e @ Cw + Cb + Ah[dst] + Bh[src] for 16-edge tiles per wave ----
__global__ __launch_bounds__(256) void edge_en(
    const __half* __restrict__ ep,
    const int* __restrict__ srcp, const int* __restrict__ dstp,
    const __half* __restrict__ Ah, const __half* __restrict__ Bh,
    const float* __restrict__ Cw, const float* __restrict__ Cb,
    __half* __restrict__ enh, float* __restrict__ partial, int E)
{
    __shared__ float red[256];
    int tid = threadIdx.x;
    int lane = tid & 63;
    int m = lane & 15, q = lane >> 4;
    half8_t b0, b1;
#pragma unroll
    for (int i = 0; i < 8; i++) {
        int k = q * 8 + i;
        b0[i] = (_Float16)Cw[k * 32 + m];
        b1[i] = (_Float16)Cw[k * 32 + m + 16];
    }
    float cb0 = Cb[m], cb1 = Cb[m + 16];
    float es0 = 0.f, eq0 = 0.f, es1 = 0.f, eq1 = 0.f;

    int ntile = (E + 15) >> 4;
    int wid = blockIdx.x * 4 + (tid >> 6);
    int nwave = gridDim.x * 4;
    for (int t = wid; t < ntile; t += nwave) {
        int base = t << 4;
        int arow = base + m;
        if (arow >= E) arow = E - 1;
        half8_t a = *(const half8_t*)(ep + (size_t)arow * 32 + q * 8);
        float4_t acc0 = __builtin_amdgcn_mfma_f32_16x16x32_f16(a, b0, (float4_t){0.f,0.f,0.f,0.f}, 0, 0, 0);
        float4_t acc1 = __builtin_amdgcn_mfma_f32_16x16x32_f16(a, b1, (float4_t){0.f,0.f,0.f,0.f}, 0, 0, 0);
#pragma unroll
        for (int reg = 0; reg < 4; reg++) {
            int row = q * 4 + reg;
            int edge = base + row;
            if (edge < E) {
                int s = srcp[edge], d = dstp[edge];
                float ah0 = __half2float(Ah[(size_t)d * 32 + m]);
                float bh0 = __half2float(Bh[(size_t)s * 32 + m]);
                float ah1 = __half2float(Ah[(size_t)d * 32 + m + 16]);
                float bh1 = __half2float(Bh[(size_t)s * 32 + m + 16]);
                float en0 = acc0[reg] + cb0 + ah0 + bh0;
                float en1 = acc1[reg] + cb1 + ah1 + bh1;
                enh[(size_t)edge * 32 + m]      = __float2half_rn(en0);
                enh[(size_t)edge * 32 + m + 16] = __float2half_rn(en1);
                es0 += en0; eq0 += en0 * en0;
                es1 += en1; eq1 += en1 * en1;
            }
        }
    }
    float* p = partial + (size_t)blockIdx.x * 64;
    __syncthreads();
    red[tid] = es0;
    __syncthreads();
    if (tid < 16) {
        float s = 0.f;
#pragma unroll
        for (int w = 0; w < 4; w++)
#pragma unroll
            for (int k = 0; k < 4; k++) s += red[w * 64 + k * 16 + tid];
        p[tid] = s;
    }
    __syncthreads();
    red[tid] = es1;
    __syncthreads();
    if (tid < 16) {
        float s = 0.f;
#pragma unroll
        for (int w = 0; w < 4; w++)
#pragma unroll
            for (int k = 0; k < 4; k++) s += red[w * 64 + k * 16 + tid];
        p[16 + tid] = s;
    }
    __syncthreads();
    red[tid] = eq0;
    __syncthreads();
    if (tid < 16) {
        float s = 0.f;
#pragma unroll
        for (int w = 0; w < 4; w++)
#pragma unroll
            for (int k = 0; k < 4; k++) s += red[w * 64 + k * 16 + tid];
        p[32 + tid] = s;
    }
    __syncthreads();
    red[tid] = eq1;
    __syncthreads();
    if (tid < 16) {
        float s = 0.f;
#pragma unroll
        for (int w = 0; w < 4; w++)
#pragma unroll
            for (int k = 0; k < 4; k++) s += red[w * 64 + k * 16 + tid];
        p[48 + tid] = s;
    }
}

// ---- phase B: half2 CSR walk; 16 lanes/node, 2 cols/lane; fused e-apply; h-BN partials ----
__global__ __launch_bounds__(256) void node_agg(
    const __half* __restrict__ enh, const int* __restrict__ srcp,
    const int* __restrict__ offsets, const int* __restrict__ counts,
    const __half* __restrict__ Vh, float* __restrict__ hnew,
    __half* __restrict__ ep, const float* __restrict__ sc_e, const float* __restrict__ sh_e,
    float* __restrict__ partial, int N)
{
    __shared__ float red[512];
    int tid = threadIdx.x, u = tid & 15, grp = tid >> 4;   // 16 groups of 16 lanes
    int c0 = 2 * u;
    float sc0 = sc_e[c0], sh0 = sh_e[c0];
    float sc1 = sc_e[c0 + 1], sh1 = sh_e[c0 + 1];
    float hs0 = 0.f, hq0 = 0.f, hs1 = 0.f, hq1 = 0.f;
    for (int nb0 = blockIdx.x * 16; nb0 < N; nb0 += gridDim.x * 16) {
        int node = nb0 + grp;
        if (node >= N) break;
        int start = offsets[node], len = counts[node];
        float num0 = 0.f, den0 = 0.f, num1 = 0.f, den1 = 0.f;
        int qq = 0;
        for (; qq + 2 <= len; qq += 2) {
            int p0 = start + qq, p1 = p0 + 1;
            int s0 = srcp[p0], s1 = srcp[p1];
            float2 en0 = __half22float2(*(const __half2*)(enh + (size_t)p0 * 32 + c0));
            float2 en1 = __half22float2(*(const __half2*)(enh + (size_t)p1 * 32 + c0));
            float2 vh0 = __half22float2(*(const __half2*)(Vh + (size_t)s0 * 32 + c0));
            float2 vh1 = __half22float2(*(const __half2*)(Vh + (size_t)s1 * 32 + c0));
            float2 e0 = __half22float2(*(const __half2*)(ep + (size_t)p0 * 32 + c0));
            float2 e1 = __half22float2(*(const __half2*)(ep + (size_t)p1 * 32 + c0));
            float sg00 = 1.f / (1.f + __expf(-en0.x)), sg01 = 1.f / (1.f + __expf(-en0.y));
            float sg10 = 1.f / (1.f + __expf(-en1.x)), sg11 = 1.f / (1.f + __expf(-en1.y));
            num0 = fmaf(sg00, vh0.x, num0); num1 = fmaf(sg01, vh0.y, num1);
            num0 = fmaf(sg10, vh1.x, num0); num1 = fmaf(sg11, vh1.y, num1);
            den0 += sg00 + sg10; den1 += sg01 + sg11;
            *(__half2*)(ep + (size_t)p0 * 32 + c0) = __floats2half2_rn(
                e0.x + fmaxf(fmaf(en0.x, sc0, sh0), 0.f),
                e0.y + fmaxf(fmaf(en0.y, sc1, sh1), 0.f));
            *(__half2*)(ep + (size_t)p1 * 32 + c0) = __floats2half2_rn(
                e1.x + fmaxf(fmaf(en1.x, sc0, sh0), 0.f),
                e1.y + fmaxf(fmaf(en1.y, sc1, sh1), 0.f));
        }
        if (qq < len) {
            int p0 = start + qq;
            int s0 = srcp[p0];
            float2 en0 = __half22float2(*(const __half2*)(enh + (size_t)p0 * 32 + c0));
            float2 vh0 = __half22float2(*(const __half2*)(Vh + (size_t)s0 * 32 + c0));
            float2 e0 = __half22float2(*(const __half2*)(ep + (size_t)p0 * 32 + c0));
            float sg00 = 1.f / (1.f + __expf(-en0.x)), sg01 = 1.f / (1.f + __expf(-en0.y));
            num0 = fmaf(sg00, vh0.x, num0); num1 = fmaf(sg01, vh0.y, num1);
            den0 += sg00; den1 += sg01;
            *(__half2*)(ep + (size_t)p0 * 32 + c0) = __floats2half2_rn(
                e0.x + fmaxf(fmaf(en0.x, sc0, sh0), 0.f),
                e0.y + fmaxf(fmaf(en0.y, sc1, sh1), 0.f));
        }
        size_t ho = (size_t)node * 32 + c0;
        float hv0 = hnew[ho]     + num0 / (den0 + 1e-6f);   // hnew holds Uh
        float hv1 = hnew[ho + 1] + num1 / (den1 + 1e-6f);
        *(float2*)(hnew + ho) = make_float2(hv0, hv1);
        hs0 += hv0; hq0 += hv0 * hv0;
        hs1 += hv1; hq1 += hv1 * hv1;
    }
    __syncthreads();
    red[tid] = hs0; red[256 + tid] = hs1;
    __syncthreads();
    float* p = partial + (size_t)blockIdx.x * 64;
    if (tid < 32) {
        int uu = tid >> 1, par = tid & 1;
        const float* r = red + par * 256;
        float s = 0.f;
#pragma unroll
        for (int g = 0; g < 16; g++) s += r[g * 16 + uu];
        p[tid] = s;
    }
    __syncthreads();
    red[tid] = hq0; red[256 + tid] = hq1;
    __syncthreads();
    if (tid < 32) {
        int uu = tid >> 1, par = tid & 1;
        const float* r = red + par * 256;
        float s = 0.f;
#pragma unroll
        for (int g = 0; g < 16; g++) s += r[g * 16 + uu];
        p[32 + tid] = s;
    }
}

// ---------------- finalize BN stats for one side: 32 blocks, one per feature ----------------
__global__ __launch_bounds__(256) void stats_side(
    const float* __restrict__ partial, int nrows, double cnt,
    const float* __restrict__ g, const float* __restrict__ b,
    float* __restrict__ sc_out, float* __restrict__ sh_out)
{
    int j = blockIdx.x;
    __shared__ double rs[256], rq[256];
    double s = 0.0, q = 0.0;
    for (int r = threadIdx.x; r < nrows; r += 256) {
        s += (double)partial[(size_t)r * 64 + j];
        q += (double)partial[(size_t)r * 64 + 32 + j];
    }
    rs[threadIdx.x] = s; rq[threadIdx.x] = q;
    __syncthreads();
    for (int off = 128; off; off >>= 1) {
        if (threadIdx.x < off) { rs[threadIdx.x] += rs[threadIdx.x + off]; rq[threadIdx.x] += rq[threadIdx.x + off]; }
        __syncthreads();
    }
    if (threadIdx.x == 0) {
        double mean = rs[0] / cnt;
        double var = rq[0] / cnt - mean * mean;
        float scale = g[j] * (float)(1.0 / sqrt(var + 1e-5));
        sc_out[j] = scale;
        sh_out[j] = b[j] - (float)mean * scale;
    }
}

// ---- final h apply: h16 = fp16(h + relu(hnew*sc+sh)) into a separate buffer ----
__global__ void apply4_h16(const float4* __restrict__ pre, const float* __restrict__ scale,
                           const float* __restrict__ shift, const float4* __restrict__ hold,
                           __half2* __restrict__ h16, size_t n4)
{
    size_t i = (size_t)blockIdx.x * 256 + threadIdx.x;
    if (i < n4) {
        int j4 = (int)(i & 7) * 4;
        float4 sc = *(const float4*)(scale + j4);
        float4 sh = *(const float4*)(shift + j4);
        float4 p = pre[i], a = hold[i];
        a.x += fmaxf(fmaf(p.x, sc.x, sh.x), 0.f);
        a.y += fmaxf(fmaf(p.y, sc.y, sh.y), 0.f);
        a.z += fmaxf(fmaf(p.z, sc.z, sh.z), 0.f);
        a.w += fmaxf(fmaf(p.w, sc.w, sh.w), 0.f);
        h16[i * 2]     = __floats2half2_rn(a.x, a.y);
        h16[i * 2 + 1] = __floats2half2_rn(a.z, a.w);
    }
}

// ---- predictor (MFMA): [16-edge tile × 96] @ [96 × 32], W1/W2 epilogue, perm scatter ----
__global__ __launch_bounds__(256) void predictor(
    const __half* __restrict__ h16, const __half* __restrict__ e16,
    const int* __restrict__ srcp, const int* __restrict__ dstp, const int* __restrict__ perm,
    const float* __restrict__ W1, const float* __restrict__ b1,
    const float* __restrict__ W2, const float* __restrict__ b2v,
    float* __restrict__ out, int E)
{
    int tid = threadIdx.x;
    int lane = tid & 63;
    int m = lane & 15, q = lane >> 4;
    half8_t bf00, bf01, bf10, bf11, bf20, bf21;
#pragma unroll
    for (int i = 0; i < 8; i++) {
        int k = q * 8 + i;
        bf00[i] = (_Float16)W1[k * 32 + m];
        bf01[i] = (_Float16)W1[k * 32 + m + 16];
        bf10[i] = (_Float16)W1[(32 + k) * 32 + m];
        bf11[i] = (_Float16)W1[(32 + k) * 32 + m + 16];
        bf20[i] = (_Float16)W1[(64 + k) * 32 + m];
        bf21[i] = (_Float16)W1[(64 + k) * 32 + m + 16];
    }
    float b10 = b1[m], b11 = b1[m + 16];
    float w20 = W2[m], w21 = W2[m + 16];
    float b2 = b2v[0];

    int ntile = (E + 15) >> 4;
    int wid = blockIdx.x * 4 + (tid >> 6);
    int nwave = gridDim.x * 4;
    for (int t = wid; t < ntile; t += nwave) {
        int base = t << 4;
        int arow = base + m;
        if (arow >= E) arow = E - 1;
        int s = srcp[arow], d = dstp[arow];
        half8_t a0 = *(const half8_t*)(h16 + (size_t)s * 32 + q * 8);
        half8_t a1 = *(const half8_t*)(h16 + (size_t)d * 32 + q * 8);
        half8_t a2 = *(const half8_t*)(e16 + (size_t)arow * 32 + q * 8);
        float4_t acc0 = {0.f, 0.f, 0.f, 0.f}, acc1 = {0.f, 0.f, 0.f, 0.f};
        acc0 = __builtin_amdgcn_mfma_f32_16x16x32_f16(a0, bf00, acc0, 0, 0, 0);
        acc1 = __builtin_amdgcn_mfma_f32_16x16x32_f16(a0, bf01, acc1, 0, 0, 0);
        acc0 = __builtin_amdgcn_mfma_f32_16x16x32_f16(a1, bf10, acc0, 0, 0, 0);
        acc1 = __builtin_amdgcn_mfma_f32_16x16x32_f16(a1, bf11, acc1, 0, 0, 0);
        acc0 = __builtin_amdgcn_mfma_f32_16x16x32_f16(a2, bf20, acc0, 0, 0, 0);
        acc1 = __builtin_amdgcn_mfma_f32_16x16x32_f16(a2, bf21, acc1, 0, 0, 0);
#pragma unroll
        for (int reg = 0; reg < 4; reg++) {
            float tp = fmaxf(acc0[reg] + b10, 0.f) * w20
                     + fmaxf(acc1[reg] + b11, 0.f) * w21;
            tp += __shfl_xor(tp, 1);
            tp += __shfl_xor(tp, 2);
            tp += __shfl_xor(tp, 4);
            tp += __shfl_xor(tp, 8);
            int edge = base + q * 4 + reg;
            if (m == 0 && edge < E) out[perm[edge]] = tp + b2;
        }
    }
}

extern "C" void kernel_launch(void* const* d_in, const int* in_sizes, int n_in,
                              void* d_out, int out_size, void* d_ws, size_t ws_size,
                              hipStream_t stream)
{
    const int N = in_sizes[0];
    const int E = in_sizes[1];

    const float* x    = (const float*)d_in[0];
    const float* e_in = (const float*)d_in[1];
    const int*   eidx = (const int*)d_in[2];
    const float* pe_w = (const float*)d_in[3];
    const float* pe_b = (const float*)d_in[4];
    const float* ed_w = (const float*)d_in[5];
    const float* ed_b = (const float*)d_in[6];
    const float* Aw = (const float*)d_in[7];
    const float* Ab = (const float*)d_in[8];
    const float* Bw = (const float*)d_in[9];
    const float* Bb = (const float*)d_in[10];
    const float* Cw = (const float*)d_in[11];
    const float* Cb = (const float*)d_in[12];
    const float* Uw = (const float*)d_in[13];
    const float* Ub = (const float*)d_in[14];
    const float* Vw = (const float*)d_in[15];
    const float* Vb = (const float*)d_in[16];
    const float* bn_h_g = (const float*)d_in[17];
    const float* bn_h_b = (const float*)d_in[18];
    const float* bn_e_g = (const float*)d_in[19];
    const float* bn_e_b = (const float*)d_in[20];
    const float* W1w = (const float*)d_in[21];
    const float* W1b = (const float*)d_in[22];
    const float* W2w = (const float*)d_in[23];
    const float* W2b = (const float*)d_in[24];

    const int* srcs = eidx;
    const int* dsts = eidx + E;

    size_t nh = (size_t)N * 32;
    size_t eh = (size_t)E * 32;

    float* ws = (float*)d_ws;
    float* stats     = ws;                            // 128
    float* partial_h = stats + 128;                   // GRID_STRIDE*64
    float* partial_e = partial_h + GRID_STRIDE * 64;  // GRID_STRIDE*64
    float* h    = partial_e + GRID_STRIDE * 64;       // nh floats
    float* hnew = h + nh;                             // nh floats (Uh then h_new)
    __half* Ah  = (__half*)(hnew + nh);               // nh halves (h16 at the end)
    __half* Bh  = Ah + nh;                            // nh halves
    __half* Vh  = Bh + nh;                            // nh halves
    __half* ep  = Vh + nh;                            // eh halves (final e16 at the end)
    __half* enh = ep + eh;                            // eh halves
    int* counts    = (int*)(enh + eh);
    int* offsets   = counts + N;
    int* cursor    = offsets + N;
    int* blocksums = cursor + N;   // 128
    int* perm      = blocksums + 128;
    int* srcp      = perm + E;
    int* dstp      = srcp + E;

    size_t nh4 = nh / 4, eh4 = eh / 4;
    int gh4 = (int)((nh4 + 255) / 256);
    int ge4 = (int)((eh4 + 255) / 256);
    int gN = (N + 255) / 256;
    int gE = (E + 255) / 256;
    int nb = (N + 1023) / 1024;
    int ntileN = (N + 15) / 16;
    int gGemm = (ntileN + 3) / 4;
    if (gGemm > GRID_STRIDE) gGemm = GRID_STRIDE;

    // ---- CSR build (dst-sorted edge permutation) ----
    zero_ints<<<gN, 256, 0, stream>>>(counts, N);
    hist_kernel<<<gE, 256, 0, stream>>>(dsts, counts, E);
    scan1<<<nb, 256, 0, stream>>>(counts, offsets, blocksums, N);
    scan2<<<1, 64, 0, stream>>>(blocksums, nb);
    scan3<<<gN, 256, 0, stream>>>(offsets, blocksums, cursor, N);
    scatter_perm<<<gE, 256, 0, stream>>>(dsts, cursor, perm, E);
    gather_sd<<<gE, 256, 0, stream>>>(perm, srcs, dsts, srcp, dstp, E);

    // ---- input projections ----
    init_proj4<<<gh4, 256, 0, stream>>>(x, pe_w, pe_b, (float4*)h, nh4);
    init_ep16<<<ge4, 256, 0, stream>>>(e_in, perm, ed_w, ed_b, (__half2*)ep, eh4);

    for (int l = 0; l < NLAYERS; l++) {
        if (l == 0)
            node_gemm<0><<<gGemm, 256, 0, stream>>>(h, hnew, stats + 0, stats + 32,
                Aw + l * 1024, Ab + l * 32, Bw + l * 1024, Bb + l * 32,
                Uw + l * 1024, Ub + l * 32, Vw + l * 1024, Vb + l * 32,
                Ah, Bh, hnew, Vh, N);
        else
            node_gemm<1><<<gGemm, 256, 0, stream>>>(h, hnew, stats + 0, stats + 32,
                Aw + l * 1024, Ab + l * 32, Bw + l * 1024, Bb + l * 32,
                Uw + l * 1024, Ub + l * 32, Vw + l * 1024, Vb + l * 32,
                Ah, Bh, hnew, Vh, N);
        edge_en<<<GRID_STRIDE, 256, 0, stream>>>(ep, srcp, dstp, Ah, Bh,
            Cw + l * 1024, Cb + l * 32, enh, partial_e, E);
        stats_side<<<32, 256, 0, stream>>>(partial_e, GRID_STRIDE, (double)E,
            bn_e_g + l * 32, bn_e_b + l * 32, stats + 64, stats + 96);
        node_agg<<<GRID_STRIDE, 256, 0, stream>>>(enh, srcp, offsets, counts,
            Vh, hnew, ep, stats + 64, stats + 96, partial_h, N);
        stats_side<<<32, 256, 0, stream>>>(partial_h, GRID_STRIDE, (double)N,
            bn_h_g + l * 32, bn_h_b + l * 32, stats + 0, stats + 32);
    }

    // final h-update straight to fp16 (Ah already consumed by edge_en l=3)
    apply4_h16<<<gh4, 256, 0, stream>>>((const float4*)hnew, stats + 0, stats + 32,
                                        (const float4*)h, (__half2*)Ah, nh4);

    predictor<<<GRID_STRIDE, 256, 0, stream>>>((const __half*)Ah, (const __half*)ep,
                                               srcp, dstp, perm, W1w, W1b, W2w, W2b,
                                               (float*)d_out, E);
}

// Round 17
// 737.970 us; speedup vs baseline: 1.1621x; 1.0009x over previous
//
#include <hip/hip_runtime.h>
#include <hip/hip_bf16.h>
#include <hip/hip_fp16.h>

#define NLAYERS 4
#define GRID_STRIDE 2048

typedef _Float16 half8_t __attribute__((ext_vector_type(8)));
typedef float float4_t __attribute__((ext_vector_type(4)));
typedef float float8_t __attribute__((ext_vector_type(8)));

// ---------------- small zero kernel ----------------
__global__ void zero_ints(int* __restrict__ p, int n)
{
    int i = blockIdx.x * 256 + threadIdx.x;
    if (i < n) p[i] = 0;
}

// ---------------- CSR build ----------------
__global__ void hist_kernel(const int* __restrict__ dsts, int* __restrict__ counts, int E)
{
    int i = blockIdx.x * 256 + threadIdx.x;
    if (i < E) atomicAdd(&counts[dsts[i]], 1);
}

__global__ __launch_bounds__(256) void scan1(const int* __restrict__ counts,
                                             int* __restrict__ offsets,
                                             int* __restrict__ blocksums, int N)
{
    __shared__ int sdata[256];
    int t = threadIdx.x;
    int bbase = blockIdx.x * 1024;
    int v[4]; int s = 0;
#pragma unroll
    for (int q = 0; q < 4; q++) {
        int idx = bbase + t * 4 + q;
        v[q] = (idx < N) ? counts[idx] : 0;
        s += v[q];
    }
    sdata[t] = s;
    __syncthreads();
    for (int off = 1; off < 256; off <<= 1) {
        int x = (t >= off) ? sdata[t - off] : 0;
        __syncthreads();
        sdata[t] += x;
        __syncthreads();
    }
    int excl = sdata[t] - s;
    int run = excl;
#pragma unroll
    for (int q = 0; q < 4; q++) {
        int idx = bbase + t * 4 + q;
        if (idx < N) offsets[idx] = run;
        run += v[q];
    }
    if (t == 255) blocksums[blockIdx.x] = sdata[255];
}

__global__ void scan2(int* __restrict__ blocksums, int nb)
{
    if (threadIdx.x == 0 && blockIdx.x == 0) {
        int run = 0;
        for (int b = 0; b < nb; b++) { int t = blocksums[b]; blocksums[b] = run; run += t; }
    }
}

__global__ void scan3(int* __restrict__ offsets, const int* __restrict__ blocksums,
                      int* __restrict__ cursor, int N)
{
    int i = blockIdx.x * 256 + threadIdx.x;
    if (i < N) {
        int v = offsets[i] + blocksums[i >> 10];
        offsets[i] = v;
        cursor[i] = v;
    }
}

// scatter only perm; non-temporal store to dodge partial-line writeback amplification
__global__ void scatter_perm(const int* __restrict__ dsts, int* __restrict__ cursor,
                             int* __restrict__ perm, int E)
{
    int i = blockIdx.x * 256 + threadIdx.x;
    if (i < E) {
        int slot = atomicAdd(&cursor[dsts[i]], 1);
        __builtin_nontemporal_store(i, &perm[slot]);
    }
}

__global__ void gather_sd(const int* __restrict__ perm, const int* __restrict__ srcs,
                          const int* __restrict__ dsts, int* __restrict__ srcp,
                          int* __restrict__ dstp, int E)
{
    int i = blockIdx.x * 256 + threadIdx.x;
    if (i < E) {
        int e = perm[i];
        srcp[i] = srcs[e];
        dstp[i] = dsts[e];
    }
}

// ---------------- init projections ----------------
__global__ void init_proj4(const float* __restrict__ in, const float* __restrict__ w,
                           const float* __restrict__ b, float4* __restrict__ out, size_t n4)
{
    size_t i = (size_t)blockIdx.x * 256 + threadIdx.x;
    if (i < n4) {
        int j4 = (int)(i & 7) * 4;
        float xv = in[i >> 3];
        float4 wv = *(const float4*)(w + j4);
        float4 bv = *(const float4*)(b + j4);
        out[i] = make_float4(fmaf(xv, wv.x, bv.x), fmaf(xv, wv.y, bv.y),
                             fmaf(xv, wv.z, bv.z), fmaf(xv, wv.w, bv.w));
    }
}

__global__ void init_ep16(const float* __restrict__ e_in, const int* __restrict__ perm,
                          const float* __restrict__ w, const float* __restrict__ b,
                          __half2* __restrict__ out, size_t n4)
{
    size_t i = (size_t)blockIdx.x * 256 + threadIdx.x;
    if (i < n4) {
        int row = (int)(i >> 3);
        float xv = e_in[perm[row]];
        int j4 = (int)(i & 7) * 4;
        float4 wv = *(const float4*)(w + j4);
        float4 bv = *(const float4*)(b + j4);
        out[i * 2]     = __floats2half2_rn(fmaf(xv, wv.x, bv.x), fmaf(xv, wv.y, bv.y));
        out[i * 2 + 1] = __floats2half2_rn(fmaf(xv, wv.z, bv.z), fmaf(xv, wv.w, bv.w));
    }
}

// ---- node GEMMs (MFMA): 16-node tile per wave; A=fp16(h row); 4 matrices x 2 col tiles.
// FUSE: during A-load applies prev layer h-update: h += relu(hnew*sc+sh), writes h back.
template <int FUSE>
__global__ __launch_bounds__(256) void node_gemm(
    float* __restrict__ h, const float* __restrict__ hnew_in,
    const float* __restrict__ sc_h, const float* __restrict__ sh_h,
    const float* __restrict__ Aw, const float* __restrict__ Ab,
    const float* __restrict__ Bw, const float* __restrict__ Bb,
    const float* __restrict__ Uw, const float* __restrict__ Ub,
    const float* __restrict__ Vw, const float* __restrict__ Vb,
    __half* __restrict__ Ahh, __half* __restrict__ Bhh,
    float* __restrict__ Uhh, __half* __restrict__ Vhh, int N)
{
    int tid = threadIdx.x;
    int lane = tid & 63;
    int m = lane & 15, q = lane >> 4;
    half8_t bA0, bA1, bB0, bB1, bU0, bU1, bV0, bV1;
    float scq[8], shq[8];
#pragma unroll
    for (int i = 0; i < 8; i++) {
        int k = q * 8 + i;
        bA0[i] = (_Float16)Aw[k * 32 + m];  bA1[i] = (_Float16)Aw[k * 32 + m + 16];
        bB0[i] = (_Float16)Bw[k * 32 + m];  bB1[i] = (_Float16)Bw[k * 32 + m + 16];
        bU0[i] = (_Float16)Uw[k * 32 + m];  bU1[i] = (_Float16)Uw[k * 32 + m + 16];
        bV0[i] = (_Float16)Vw[k * 32 + m];  bV1[i] = (_Float16)Vw[k * 32 + m + 16];
        if (FUSE) { scq[i] = sc_h[k]; shq[i] = sh_h[k]; }
    }
    float ab0 = Ab[m], ab1 = Ab[m + 16];
    float bb0 = Bb[m], bb1 = Bb[m + 16];
    float ub0 = Ub[m], ub1 = Ub[m + 16];
    float vb0 = Vb[m], vb1 = Vb[m + 16];

    int ntile = (N + 15) >> 4;
    int wid = blockIdx.x * 4 + (tid >> 6);
    int nwave = gridDim.x * 4;
    for (int t = wid; t < ntile; t += nwave) {
        int base = t << 4;
        int arow = base + m;
        bool valid = arow < N;
        if (!valid) arow = N - 1;
        float8_t hv = *(const float8_t*)(h + (size_t)arow * 32 + q * 8);
        if (FUSE) {
            float8_t pv = *(const float8_t*)(hnew_in + (size_t)arow * 32 + q * 8);
#pragma unroll
            for (int i = 0; i < 8; i++)
                hv[i] += fmaxf(fmaf(pv[i], scq[i], shq[i]), 0.f);
            if (valid) *(float8_t*)(h + (size_t)arow * 32 + q * 8) = hv;
        }
        half8_t a;
#pragma unroll
        for (int i = 0; i < 8; i++) a[i] = (_Float16)hv[i];
        float4_t aA0 = __builtin_amdgcn_mfma_f32_16x16x32_f16(a, bA0, (float4_t){0,0,0,0}, 0, 0, 0);
        float4_t aA1 = __builtin_amdgcn_mfma_f32_16x16x32_f16(a, bA1, (float4_t){0,0,0,0}, 0, 0, 0);
        float4_t aB0 = __builtin_amdgcn_mfma_f32_16x16x32_f16(a, bB0, (float4_t){0,0,0,0}, 0, 0, 0);
        float4_t aB1 = __builtin_amdgcn_mfma_f32_16x16x32_f16(a, bB1, (float4_t){0,0,0,0}, 0, 0, 0);
        float4_t aU0 = __builtin_amdgcn_mfma_f32_16x16x32_f16(a, bU0, (float4_t){0,0,0,0}, 0, 0, 0);
        float4_t aU1 = __builtin_amdgcn_mfma_f32_16x16x32_f16(a, bU1, (float4_t){0,0,0,0}, 0, 0, 0);
        float4_t aV0 = __builtin_amdgcn_mfma_f32_16x16x32_f16(a, bV0, (float4_t){0,0,0,0}, 0, 0, 0);
        float4_t aV1 = __builtin_amdgcn_mfma_f32_16x16x32_f16(a, bV1, (float4_t){0,0,0,0}, 0, 0, 0);
#pragma unroll
        for (int reg = 0; reg < 4; reg++) {
            int node = base + q * 4 + reg;
            if (node < N) {
                size_t o = (size_t)node * 32;
                Ahh[o + m]      = __float2half_rn(aA0[reg] + ab0);
                Ahh[o + m + 16] = __float2half_rn(aA1[reg] + ab1);
                Bhh[o + m]      = __float2half_rn(aB0[reg] + bb0);
                Bhh[o + m + 16] = __float2half_rn(aB1[reg] + bb1);
                Vhh[o + m]      = __float2half_rn(aV0[reg] + vb0);
                Vhh[o + m + 16] = __float2half_rn(aV1[reg] + vb1);
                Uhh[o + m]      = aU0[reg] + ub0;
                Uhh[o + m + 16] = aU1[reg] + ub1;
            }
        }
    }
}

// ---- phase A (MFMA): en = e @ Cw + Cb + Ah[dst] + Bh[src] for 16-edge tiles per wave ----
__global__ __launch_bounds__(256) void edge_en(
    const __half* __restrict__ ep,
    const int* __restrict__ srcp, const int* __restrict__ dstp,
    const __half* __restrict__ Ah, const __half* __restrict__ Bh,
    const float* __restrict__ Cw, const float* __restrict__ Cb,
    __half* __restrict__ enh, float* __restrict__ partial, int E)
{
    __shared__ float red[256];
    int tid = threadIdx.x;
    int lane = tid & 63;
    int m = lane & 15, q = lane >> 4;
    half8_t b0, b1;
#pragma unroll
    for (int i = 0; i < 8; i++) {
        int k = q * 8 + i;
        b0[i] = (_Float16)Cw[k * 32 + m];
        b1[i] = (_Float16)Cw[k * 32 + m + 16];
    }
    float cb0 = Cb[m], cb1 = Cb[m + 16];
    float es0 = 0.f, eq0 = 0.f, es1 = 0.f, eq1 = 0.f;

    int ntile = (E + 15) >> 4;
    int wid = blockIdx.x * 4 + (tid >> 6);
    int nwave = gridDim.x * 4;
    for (int t = wid; t < ntile; t += nwave) {
        int base = t << 4;
        int arow = base + m;
        if (arow >= E) arow = E - 1;
        half8_t a = *(const half8_t*)(ep + (size_t)arow * 32 + q * 8);
        float4_t acc0 = __builtin_amdgcn_mfma_f32_16x16x32_f16(a, b0, (float4_t){0.f,0.f,0.f,0.f}, 0, 0, 0);
        float4_t acc1 = __builtin_amdgcn_mfma_f32_16x16x32_f16(a, b1, (float4_t){0.f,0.f,0.f,0.f}, 0, 0, 0);
#pragma unroll
        for (int reg = 0; reg < 4; reg++) {
            int row = q * 4 + reg;
            int edge = base + row;
            if (edge < E) {
                int s = srcp[edge], d = dstp[edge];
                float ah0 = __half2float(Ah[(size_t)d * 32 + m]);
                float bh0 = __half2float(Bh[(size_t)s * 32 + m]);
                float ah1 = __half2float(Ah[(size_t)d * 32 + m + 16]);
                float bh1 = __half2float(Bh[(size_t)s * 32 + m + 16]);
                float en0 = acc0[reg] + cb0 + ah0 + bh0;
                float en1 = acc1[reg] + cb1 + ah1 + bh1;
                enh[(size_t)edge * 32 + m]      = __float2half_rn(en0);
                enh[(size_t)edge * 32 + m + 16] = __float2half_rn(en1);
                es0 += en0; eq0 += en0 * en0;
                es1 += en1; eq1 += en1 * en1;
            }
        }
    }
    float* p = partial + (size_t)blockIdx.x * 64;
    __syncthreads();
    red[tid] = es0;
    __syncthreads();
    if (tid < 16) {
        float s = 0.f;
#pragma unroll
        for (int w = 0; w < 4; w++)
#pragma unroll
            for (int k = 0; k < 4; k++) s += red[w * 64 + k * 16 + tid];
        p[tid] = s;
    }
    __syncthreads();
    red[tid] = es1;
    __syncthreads();
    if (tid < 16) {
        float s = 0.f;
#pragma unroll
        for (int w = 0; w < 4; w++)
#pragma unroll
            for (int k = 0; k < 4; k++) s += red[w * 64 + k * 16 + tid];
        p[16 + tid] = s;
    }
    __syncthreads();
    red[tid] = eq0;
    __syncthreads();
    if (tid < 16) {
        float s = 0.f;
#pragma unroll
        for (int w = 0; w < 4; w++)
#pragma unroll
            for (int k = 0; k < 4; k++) s += red[w * 64 + k * 16 + tid];
        p[32 + tid] = s;
    }
    __syncthreads();
    red[tid] = eq1;
    __syncthreads();
    if (tid < 16) {
        float s = 0.f;
#pragma unroll
        for (int w = 0; w < 4; w++)
#pragma unroll
            for (int k = 0; k < 4; k++) s += red[w * 64 + k * 16 + tid];
        p[48 + tid] = s;
    }
}

// ---- phase B: half2 CSR walk; 16 lanes/node, 2 cols/lane; fused e-apply; h-BN partials ----
__global__ __launch_bounds__(256) void node_agg(
    const __half* __restrict__ enh, const int* __restrict__ srcp,
    const int* __restrict__ offsets, const int* __restrict__ counts,
    const __half* __restrict__ Vh, float* __restrict__ hnew,
    __half* __restrict__ ep, const float* __restrict__ sc_e, const float* __restrict__ sh_e,
    float* __restrict__ partial, int N)
{
    __shared__ float red[512];
    int tid = threadIdx.x, u = tid & 15, grp = tid >> 4;   // 16 groups of 16 lanes
    int c0 = 2 * u;
    float sc0 = sc_e[c0], sh0 = sh_e[c0];
    float sc1 = sc_e[c0 + 1], sh1 = sh_e[c0 + 1];
    float hs0 = 0.f, hq0 = 0.f, hs1 = 0.f, hq1 = 0.f;
    for (int nb0 = blockIdx.x * 16; nb0 < N; nb0 += gridDim.x * 16) {
        int node = nb0 + grp;
        if (node >= N) break;
        int start = offsets[node], len = counts[node];
        float num0 = 0.f, den0 = 0.f, num1 = 0.f, den1 = 0.f;
        int qq = 0;
        for (; qq + 2 <= len; qq += 2) {
            int p0 = start + qq, p1 = p0 + 1;
            int s0 = srcp[p0], s1 = srcp[p1];
            float2 en0 = __half22float2(*(const __half2*)(enh + (size_t)p0 * 32 + c0));
            float2 en1 = __half22float2(*(const __half2*)(enh + (size_t)p1 * 32 + c0));
            float2 vh0 = __half22float2(*(const __half2*)(Vh + (size_t)s0 * 32 + c0));
            float2 vh1 = __half22float2(*(const __half2*)(Vh + (size_t)s1 * 32 + c0));
            float2 e0 = __half22float2(*(const __half2*)(ep + (size_t)p0 * 32 + c0));
            float2 e1 = __half22float2(*(const __half2*)(ep + (size_t)p1 * 32 + c0));
            float sg00 = 1.f / (1.f + __expf(-en0.x)), sg01 = 1.f / (1.f + __expf(-en0.y));
            float sg10 = 1.f / (1.f + __expf(-en1.x)), sg11 = 1.f / (1.f + __expf(-en1.y));
            num0 = fmaf(sg00, vh0.x, num0); num1 = fmaf(sg01, vh0.y, num1);
            num0 = fmaf(sg10, vh1.x, num0); num1 = fmaf(sg11, vh1.y, num1);
            den0 += sg00 + sg10; den1 += sg01 + sg11;
            *(__half2*)(ep + (size_t)p0 * 32 + c0) = __floats2half2_rn(
                e0.x + fmaxf(fmaf(en0.x, sc0, sh0), 0.f),
                e0.y + fmaxf(fmaf(en0.y, sc1, sh1), 0.f));
            *(__half2*)(ep + (size_t)p1 * 32 + c0) = __floats2half2_rn(
                e1.x + fmaxf(fmaf(en1.x, sc0, sh0), 0.f),
                e1.y + fmaxf(fmaf(en1.y, sc1, sh1), 0.f));
        }
        if (qq < len) {
            int p0 = start + qq;
            int s0 = srcp[p0];
            float2 en0 = __half22float2(*(const __half2*)(enh + (size_t)p0 * 32 + c0));
            float2 vh0 = __half22float2(*(const __half2*)(Vh + (size_t)s0 * 32 + c0));
            float2 e0 = __half22float2(*(const __half2*)(ep + (size_t)p0 * 32 + c0));
            float sg00 = 1.f / (1.f + __expf(-en0.x)), sg01 = 1.f / (1.f + __expf(-en0.y));
            num0 = fmaf(sg00, vh0.x, num0); num1 = fmaf(sg01, vh0.y, num1);
            den0 += sg00; den1 += sg01;
            *(__half2*)(ep + (size_t)p0 * 32 + c0) = __floats2half2_rn(
                e0.x + fmaxf(fmaf(en0.x, sc0, sh0), 0.f),
                e0.y + fmaxf(fmaf(en0.y, sc1, sh1), 0.f));
        }
        size_t ho = (size_t)node * 32 + c0;
        float hv0 = hnew[ho]     + num0 / (den0 + 1e-6f);   // hnew holds Uh
        float hv1 = hnew[ho + 1] + num1 / (den1 + 1e-6f);
        *(float2*)(hnew + ho) = make_float2(hv0, hv1);
        hs0 += hv0; hq0 += hv0 * hv0;
        hs1 += hv1; hq1 += hv1 * hv1;
    }
    __syncthreads();
    red[tid] = hs0; red[256 + tid] = hs1;
    __syncthreads();
    float* p = partial + (size_t)blockIdx.x * 64;
    if (tid < 32) {
        int uu = tid >> 1, par = tid & 1;
        const float* r = red + par * 256;
        float s = 0.f;
#pragma unroll
        for (int g = 0; g < 16; g++) s += r[g * 16 + uu];
        p[tid] = s;
    }
    __syncthreads();
    red[tid] = hq0; red[256 + tid] = hq1;
    __syncthreads();
    if (tid < 32) {
        int uu = tid >> 1, par = tid & 1;
        const float* r = red + par * 256;
        float s = 0.f;
#pragma unroll
        for (int g = 0; g < 16; g++) s += r[g * 16 + uu];
        p[32 + tid] = s;
    }
}

// ---------------- finalize BN stats for one side: 32 blocks, one per feature ----------------
__global__ __launch_bounds__(256) void stats_side(
    const float* __restrict__ partial, int nrows, double cnt,
    const float* __restrict__ g, const float* __restrict__ b,
    float* __restrict__ sc_out, float* __restrict__ sh_out)
{
    int j = blockIdx.x;
    __shared__ double rs[256], rq[256];
    double s = 0.0, q = 0.0;
    for (int r = threadIdx.x; r < nrows; r += 256) {
        s += (double)partial[(size_t)r * 64 + j];
        q += (double)partial[(size_t)r * 64 + 32 + j];
    }
    rs[threadIdx.x] = s; rq[threadIdx.x] = q;
    __syncthreads();
    for (int off = 128; off; off >>= 1) {
        if (threadIdx.x < off) { rs[threadIdx.x] += rs[threadIdx.x + off]; rq[threadIdx.x] += rq[threadIdx.x + off]; }
        __syncthreads();
    }
    if (threadIdx.x == 0) {
        double mean = rs[0] / cnt;
        double var = rq[0] / cnt - mean * mean;
        float scale = g[j] * (float)(1.0 / sqrt(var + 1e-5));
        sc_out[j] = scale;
        sh_out[j] = b[j] - (float)mean * scale;
    }
}

// ---- final h apply: h16 = fp16(h + relu(hnew*sc+sh)) into a separate buffer ----
__global__ void apply4_h16(const float4* __restrict__ pre, const float* __restrict__ scale,
                           const float* __restrict__ shift, const float4* __restrict__ hold,
                           __half2* __restrict__ h16, size_t n4)
{
    size_t i = (size_t)blockIdx.x * 256 + threadIdx.x;
    if (i < n4) {
        int j4 = (int)(i & 7) * 4;
        float4 sc = *(const float4*)(scale + j4);
        float4 sh = *(const float4*)(shift + j4);
        float4 p = pre[i], a = hold[i];
        a.x += fmaxf(fmaf(p.x, sc.x, sh.x), 0.f);
        a.y += fmaxf(fmaf(p.y, sc.y, sh.y), 0.f);
        a.z += fmaxf(fmaf(p.z, sc.z, sh.z), 0.f);
        a.w += fmaxf(fmaf(p.w, sc.w, sh.w), 0.f);
        h16[i * 2]     = __floats2half2_rn(a.x, a.y);
        h16[i * 2 + 1] = __floats2half2_rn(a.z, a.w);
    }
}

// ---- predictor (MFMA): [16-edge tile × 96] @ [96 × 32], W1/W2 epilogue, NT perm scatter ----
__global__ __launch_bounds__(256) void predictor(
    const __half* __restrict__ h16, const __half* __restrict__ e16,
    const int* __restrict__ srcp, const int* __restrict__ dstp, const int* __restrict__ perm,
    const float* __restrict__ W1, const float* __restrict__ b1,
    const float* __restrict__ W2, const float* __restrict__ b2v,
    float* __restrict__ out, int E)
{
    int tid = threadIdx.x;
    int lane = tid & 63;
    int m = lane & 15, q = lane >> 4;
    half8_t bf00, bf01, bf10, bf11, bf20, bf21;
#pragma unroll
    for (int i = 0; i < 8; i++) {
        int k = q * 8 + i;
        bf00[i] = (_Float16)W1[k * 32 + m];
        bf01[i] = (_Float16)W1[k * 32 + m + 16];
        bf10[i] = (_Float16)W1[(32 + k) * 32 + m];
        bf11[i] = (_Float16)W1[(32 + k) * 32 + m + 16];
        bf20[i] = (_Float16)W1[(64 + k) * 32 + m];
        bf21[i] = (_Float16)W1[(64 + k) * 32 + m + 16];
    }
    float b10 = b1[m], b11 = b1[m + 16];
    float w20 = W2[m], w21 = W2[m + 16];
    float b2 = b2v[0];

    int ntile = (E + 15) >> 4;
    int wid = blockIdx.x * 4 + (tid >> 6);
    int nwave = gridDim.x * 4;
    for (int t = wid; t < ntile; t += nwave) {
        int base = t << 4;
        int arow = base + m;
        if (arow >= E) arow = E - 1;
        int s = srcp[arow], d = dstp[arow];
        half8_t a0 = *(const half8_t*)(h16 + (size_t)s * 32 + q * 8);
        half8_t a1 = *(const half8_t*)(h16 + (size_t)d * 32 + q * 8);
        half8_t a2 = *(const half8_t*)(e16 + (size_t)arow * 32 + q * 8);
        float4_t acc0 = {0.f, 0.f, 0.f, 0.f}, acc1 = {0.f, 0.f, 0.f, 0.f};
        acc0 = __builtin_amdgcn_mfma_f32_16x16x32_f16(a0, bf00, acc0, 0, 0, 0);
        acc1 = __builtin_amdgcn_mfma_f32_16x16x32_f16(a0, bf01, acc1, 0, 0, 0);
        acc0 = __builtin_amdgcn_mfma_f32_16x16x32_f16(a1, bf10, acc0, 0, 0, 0);
        acc1 = __builtin_amdgcn_mfma_f32_16x16x32_f16(a1, bf11, acc1, 0, 0, 0);
        acc0 = __builtin_amdgcn_mfma_f32_16x16x32_f16(a2, bf20, acc0, 0, 0, 0);
        acc1 = __builtin_amdgcn_mfma_f32_16x16x32_f16(a2, bf21, acc1, 0, 0, 0);
#pragma unroll
        for (int reg = 0; reg < 4; reg++) {
            float tp = fmaxf(acc0[reg] + b10, 0.f) * w20
                     + fmaxf(acc1[reg] + b11, 0.f) * w21;
            tp += __shfl_xor(tp, 1);
            tp += __shfl_xor(tp, 2);
            tp += __shfl_xor(tp, 4);
            tp += __shfl_xor(tp, 8);
            int edge = base + q * 4 + reg;
            if (m == 0 && edge < E)
                __builtin_nontemporal_store(tp + b2, &out[perm[edge]]);
        }
    }
}

extern "C" void kernel_launch(void* const* d_in, const int* in_sizes, int n_in,
                              void* d_out, int out_size, void* d_ws, size_t ws_size,
                              hipStream_t stream)
{
    const int N = in_sizes[0];
    const int E = in_sizes[1];

    const float* x    = (const float*)d_in[0];
    const float* e_in = (const float*)d_in[1];
    const int*   eidx = (const int*)d_in[2];
    const float* pe_w = (const float*)d_in[3];
    const float* pe_b = (const float*)d_in[4];
    const float* ed_w = (const float*)d_in[5];
    const float* ed_b = (const float*)d_in[6];
    const float* Aw = (const float*)d_in[7];
    const float* Ab = (const float*)d_in[8];
    const float* Bw = (const float*)d_in[9];
    const float* Bb = (const float*)d_in[10];
    const float* Cw = (const float*)d_in[11];
    const float* Cb = (const float*)d_in[12];
    const float* Uw = (const float*)d_in[13];
    const float* Ub = (const float*)d_in[14];
    const float* Vw = (const float*)d_in[15];
    const float* Vb = (const float*)d_in[16];
    const float* bn_h_g = (const float*)d_in[17];
    const float* bn_h_b = (const float*)d_in[18];
    const float* bn_e_g = (const float*)d_in[19];
    const float* bn_e_b = (const float*)d_in[20];
    const float* W1w = (const float*)d_in[21];
    const float* W1b = (const float*)d_in[22];
    const float* W2w = (const float*)d_in[23];
    const float* W2b = (const float*)d_in[24];

    const int* srcs = eidx;
    const int* dsts = eidx + E;

    size_t nh = (size_t)N * 32;
    size_t eh = (size_t)E * 32;

    float* ws = (float*)d_ws;
    float* stats     = ws;                            // 128
    float* partial_h = stats + 128;                   // GRID_STRIDE*64
    float* partial_e = partial_h + GRID_STRIDE * 64;  // GRID_STRIDE*64
    float* h    = partial_e + GRID_STRIDE * 64;       // nh floats
    float* hnew = h + nh;                             // nh floats (Uh then h_new)
    __half* Ah  = (__half*)(hnew + nh);               // nh halves (h16 at the end)
    __half* Bh  = Ah + nh;                            // nh halves
    __half* Vh  = Bh + nh;                            // nh halves
    __half* ep  = Vh + nh;                            // eh halves (final e16 at the end)
    __half* enh = ep + eh;                            // eh halves
    int* counts    = (int*)(enh + eh);
    int* offsets   = counts + N;
    int* cursor    = offsets + N;
    int* blocksums = cursor + N;   // 128
    int* perm      = blocksums + 128;
    int* srcp      = perm + E;
    int* dstp      = srcp + E;

    size_t nh4 = nh / 4, eh4 = eh / 4;
    int gh4 = (int)((nh4 + 255) / 256);
    int ge4 = (int)((eh4 + 255) / 256);
    int gN = (N + 255) / 256;
    int gE = (E + 255) / 256;
    int nb = (N + 1023) / 1024;
    int ntileN = (N + 15) / 16;
    int gGemm = (ntileN + 3) / 4;
    if (gGemm > GRID_STRIDE) gGemm = GRID_STRIDE;

    // ---- CSR build (dst-sorted edge permutation) ----
    zero_ints<<<gN, 256, 0, stream>>>(counts, N);
    hist_kernel<<<gE, 256, 0, stream>>>(dsts, counts, E);
    scan1<<<nb, 256, 0, stream>>>(counts, offsets, blocksums, N);
    scan2<<<1, 64, 0, stream>>>(blocksums, nb);
    scan3<<<gN, 256, 0, stream>>>(offsets, blocksums, cursor, N);
    scatter_perm<<<gE, 256, 0, stream>>>(dsts, cursor, perm, E);
    gather_sd<<<gE, 256, 0, stream>>>(perm, srcs, dsts, srcp, dstp, E);

    // ---- input projections ----
    init_proj4<<<gh4, 256, 0, stream>>>(x, pe_w, pe_b, (float4*)h, nh4);
    init_ep16<<<ge4, 256, 0, stream>>>(e_in, perm, ed_w, ed_b, (__half2*)ep, eh4);

    for (int l = 0; l < NLAYERS; l++) {
        if (l == 0)
            node_gemm<0><<<gGemm, 256, 0, stream>>>(h, hnew, stats + 0, stats + 32,
                Aw + l * 1024, Ab + l * 32, Bw + l * 1024, Bb + l * 32,
                Uw + l * 1024, Ub + l * 32, Vw + l * 1024, Vb + l * 32,
                Ah, Bh, hnew, Vh, N);
        else
            node_gemm<1><<<gGemm, 256, 0, stream>>>(h, hnew, stats + 0, stats + 32,
                Aw + l * 1024, Ab + l * 32, Bw + l * 1024, Bb + l * 32,
                Uw + l * 1024, Ub + l * 32, Vw + l * 1024, Vb + l * 32,
                Ah, Bh, hnew, Vh, N);
        edge_en<<<GRID_STRIDE, 256, 0, stream>>>(ep, srcp, dstp, Ah, Bh,
            Cw + l * 1024, Cb + l * 32, enh, partial_e, E);
        stats_side<<<32, 256, 0, stream>>>(partial_e, GRID_STRIDE, (double)E,
            bn_e_g + l * 32, bn_e_b + l * 32, stats + 64, stats + 96);
        node_agg<<<GRID_STRIDE, 256, 0, stream>>>(enh, srcp, offsets, counts,
            Vh, hnew, ep, stats + 64, stats + 96, partial_h, N);
        stats_side<<<32, 256, 0, stream>>>(partial_h, GRID_STRIDE, (double)N,
            bn_h_g + l * 32, bn_h_b + l * 32, stats + 0, stats + 32);
    }

    // final h-update straight to fp16 (Ah already consumed by edge_en l=3)
    apply4_h16<<<gh4, 256, 0, stream>>>((const float4*)hnew, stats + 0, stats + 32,
                                        (const float4*)h, (__half2*)Ah, nh4);

    predictor<<<GRID_STRIDE, 256, 0, stream>>>((const __half*)Ah, (const __half*)ep,
                                               srcp, dstp, perm, W1w, W1b, W2w, W2b,
                                               (float*)d_out, E);
}

// Round 18
// 713.294 us; speedup vs baseline: 1.2024x; 1.0346x over previous
//
#include <hip/hip_runtime.h>
#include <hip/hip_bf16.h>
#include <hip/hip_fp16.h>

#define NLAYERS 4
#define GRID_STRIDE 2048

typedef _Float16 half8_t __attribute__((ext_vector_type(8)));
typedef float float4_t __attribute__((ext_vector_type(4)));
typedef float float8_t __attribute__((ext_vector_type(8)));

// ---------------- small zero kernel ----------------
__global__ void zero_ints(int* __restrict__ p, int n)
{
    int i = blockIdx.x * 256 + threadIdx.x;
    if (i < n) p[i] = 0;
}

// ---------------- CSR build ----------------
__global__ void hist_kernel(const int* __restrict__ dsts, int* __restrict__ counts, int E)
{
    int i = blockIdx.x * 256 + threadIdx.x;
    if (i < E) atomicAdd(&counts[dsts[i]], 1);
}

__global__ __launch_bounds__(256) void scan1(const int* __restrict__ counts,
                                             int* __restrict__ offsets,
                                             int* __restrict__ blocksums, int N)
{
    __shared__ int sdata[256];
    int t = threadIdx.x;
    int bbase = blockIdx.x * 1024;
    int v[4]; int s = 0;
#pragma unroll
    for (int q = 0; q < 4; q++) {
        int idx = bbase + t * 4 + q;
        v[q] = (idx < N) ? counts[idx] : 0;
        s += v[q];
    }
    sdata[t] = s;
    __syncthreads();
    for (int off = 1; off < 256; off <<= 1) {
        int x = (t >= off) ? sdata[t - off] : 0;
        __syncthreads();
        sdata[t] += x;
        __syncthreads();
    }
    int excl = sdata[t] - s;
    int run = excl;
#pragma unroll
    for (int q = 0; q < 4; q++) {
        int idx = bbase + t * 4 + q;
        if (idx < N) offsets[idx] = run;
        run += v[q];
    }
    if (t == 255) blocksums[blockIdx.x] = sdata[255];
}

__global__ void scan2(int* __restrict__ blocksums, int nb)
{
    if (threadIdx.x == 0 && blockIdx.x == 0) {
        int run = 0;
        for (int b = 0; b < nb; b++) { int t = blocksums[b]; blocksums[b] = run; run += t; }
    }
}

__global__ void scan3(int* __restrict__ offsets, const int* __restrict__ blocksums,
                      int* __restrict__ cursor, int N)
{
    int i = blockIdx.x * 256 + threadIdx.x;
    if (i < N) {
        int v = offsets[i] + blocksums[i >> 10];
        offsets[i] = v;
        cursor[i] = v;
    }
}

// scatter v2: 8 dst-range groups (XCD-affine via blockIdx&7); each group scans all edges
// and writes only slots in its contiguous perm region -> single-XCD line ownership.
// Also emits inverse perm pos[i] = slot with a coalesced write.
__global__ void scatter_perm(const int* __restrict__ dsts, int* __restrict__ cursor,
                             int* __restrict__ perm, int* __restrict__ pos, int E, int N)
{
    int g = blockIdx.x & 7;
    int lo = (int)((long long)N * g >> 3);
    int hi = (int)((long long)N * (g + 1) >> 3);
    int nbg = gridDim.x >> 3;
    int bg = blockIdx.x >> 3;
    for (int i = bg * 256 + threadIdx.x; i < E; i += nbg * 256) {
        int d = dsts[i];
        if (d >= lo && d < hi) {
            int slot = atomicAdd(&cursor[d], 1);
            perm[slot] = i;
            pos[i] = slot;
        }
    }
}

__global__ void gather_sd(const int* __restrict__ perm, const int* __restrict__ srcs,
                          const int* __restrict__ dsts, int* __restrict__ srcp,
                          int* __restrict__ dstp, int E)
{
    int i = blockIdx.x * 256 + threadIdx.x;
    if (i < E) {
        int e = perm[i];
        srcp[i] = srcs[e];
        dstp[i] = dsts[e];
    }
}

// ---------------- init projections ----------------
__global__ void init_proj4(const float* __restrict__ in, const float* __restrict__ w,
                           const float* __restrict__ b, float4* __restrict__ out, size_t n4)
{
    size_t i = (size_t)blockIdx.x * 256 + threadIdx.x;
    if (i < n4) {
        int j4 = (int)(i & 7) * 4;
        float xv = in[i >> 3];
        float4 wv = *(const float4*)(w + j4);
        float4 bv = *(const float4*)(b + j4);
        out[i] = make_float4(fmaf(xv, wv.x, bv.x), fmaf(xv, wv.y, bv.y),
                             fmaf(xv, wv.z, bv.z), fmaf(xv, wv.w, bv.w));
    }
}

__global__ void init_ep16(const float* __restrict__ e_in, const int* __restrict__ perm,
                          const float* __restrict__ w, const float* __restrict__ b,
                          __half2* __restrict__ out, size_t n4)
{
    size_t i = (size_t)blockIdx.x * 256 + threadIdx.x;
    if (i < n4) {
        int row = (int)(i >> 3);
        float xv = e_in[perm[row]];
        int j4 = (int)(i & 7) * 4;
        float4 wv = *(const float4*)(w + j4);
        float4 bv = *(const float4*)(b + j4);
        out[i * 2]     = __floats2half2_rn(fmaf(xv, wv.x, bv.x), fmaf(xv, wv.y, bv.y));
        out[i * 2 + 1] = __floats2half2_rn(fmaf(xv, wv.z, bv.z), fmaf(xv, wv.w, bv.w));
    }
}

// ---- node GEMMs (MFMA): 16-node tile per wave; A=fp16(h row); 4 matrices x 2 col tiles.
// FUSE: during A-load applies prev layer h-update: h += relu(hnew*sc+sh), writes h back.
template <int FUSE>
__global__ __launch_bounds__(256) void node_gemm(
    float* __restrict__ h, const float* __restrict__ hnew_in,
    const float* __restrict__ sc_h, const float* __restrict__ sh_h,
    const float* __restrict__ Aw, const float* __restrict__ Ab,
    const float* __restrict__ Bw, const float* __restrict__ Bb,
    const float* __restrict__ Uw, const float* __restrict__ Ub,
    const float* __restrict__ Vw, const float* __restrict__ Vb,
    __half* __restrict__ Ahh, __half* __restrict__ Bhh,
    float* __restrict__ Uhh, __half* __restrict__ Vhh, int N)
{
    int tid = threadIdx.x;
    int lane = tid & 63;
    int m = lane & 15, q = lane >> 4;
    half8_t bA0, bA1, bB0, bB1, bU0, bU1, bV0, bV1;
    float scq[8], shq[8];
#pragma unroll
    for (int i = 0; i < 8; i++) {
        int k = q * 8 + i;
        bA0[i] = (_Float16)Aw[k * 32 + m];  bA1[i] = (_Float16)Aw[k * 32 + m + 16];
        bB0[i] = (_Float16)Bw[k * 32 + m];  bB1[i] = (_Float16)Bw[k * 32 + m + 16];
        bU0[i] = (_Float16)Uw[k * 32 + m];  bU1[i] = (_Float16)Uw[k * 32 + m + 16];
        bV0[i] = (_Float16)Vw[k * 32 + m];  bV1[i] = (_Float16)Vw[k * 32 + m + 16];
        if (FUSE) { scq[i] = sc_h[k]; shq[i] = sh_h[k]; }
    }
    float ab0 = Ab[m], ab1 = Ab[m + 16];
    float bb0 = Bb[m], bb1 = Bb[m + 16];
    float ub0 = Ub[m], ub1 = Ub[m + 16];
    float vb0 = Vb[m], vb1 = Vb[m + 16];

    int ntile = (N + 15) >> 4;
    int wid = blockIdx.x * 4 + (tid >> 6);
    int nwave = gridDim.x * 4;
    for (int t = wid; t < ntile; t += nwave) {
        int base = t << 4;
        int arow = base + m;
        bool valid = arow < N;
        if (!valid) arow = N - 1;
        float8_t hv = *(const float8_t*)(h + (size_t)arow * 32 + q * 8);
        if (FUSE) {
            float8_t pv = *(const float8_t*)(hnew_in + (size_t)arow * 32 + q * 8);
#pragma unroll
            for (int i = 0; i < 8; i++)
                hv[i] += fmaxf(fmaf(pv[i], scq[i], shq[i]), 0.f);
            if (valid) *(float8_t*)(h + (size_t)arow * 32 + q * 8) = hv;
        }
        half8_t a;
#pragma unroll
        for (int i = 0; i < 8; i++) a[i] = (_Float16)hv[i];
        float4_t aA0 = __builtin_amdgcn_mfma_f32_16x16x32_f16(a, bA0, (float4_t){0,0,0,0}, 0, 0, 0);
        float4_t aA1 = __builtin_amdgcn_mfma_f32_16x16x32_f16(a, bA1, (float4_t){0,0,0,0}, 0, 0, 0);
        float4_t aB0 = __builtin_amdgcn_mfma_f32_16x16x32_f16(a, bB0, (float4_t){0,0,0,0}, 0, 0, 0);
        float4_t aB1 = __builtin_amdgcn_mfma_f32_16x16x32_f16(a, bB1, (float4_t){0,0,0,0}, 0, 0, 0);
        float4_t aU0 = __builtin_amdgcn_mfma_f32_16x16x32_f16(a, bU0, (float4_t){0,0,0,0}, 0, 0, 0);
        float4_t aU1 = __builtin_amdgcn_mfma_f32_16x16x32_f16(a, bU1, (float4_t){0,0,0,0}, 0, 0, 0);
        float4_t aV0 = __builtin_amdgcn_mfma_f32_16x16x32_f16(a, bV0, (float4_t){0,0,0,0}, 0, 0, 0);
        float4_t aV1 = __builtin_amdgcn_mfma_f32_16x16x32_f16(a, bV1, (float4_t){0,0,0,0}, 0, 0, 0);
#pragma unroll
        for (int reg = 0; reg < 4; reg++) {
            int node = base + q * 4 + reg;
            if (node < N) {
                size_t o = (size_t)node * 32;
                Ahh[o + m]      = __float2half_rn(aA0[reg] + ab0);
                Ahh[o + m + 16] = __float2half_rn(aA1[reg] + ab1);
                Bhh[o + m]      = __float2half_rn(aB0[reg] + bb0);
                Bhh[o + m + 16] = __float2half_rn(aB1[reg] + bb1);
                Vhh[o + m]      = __float2half_rn(aV0[reg] + vb0);
                Vhh[o + m + 16] = __float2half_rn(aV1[reg] + vb1);
                Uhh[o + m]      = aU0[reg] + ub0;
                Uhh[o + m + 16] = aU1[reg] + ub1;
            }
        }
    }
}

// ---- phase A (MFMA): en = e @ Cw + Cb + Ah[dst] + Bh[src] for 16-edge tiles per wave ----
__global__ __launch_bounds__(256) void edge_en(
    const __half* __restrict__ ep,
    const int* __restrict__ srcp, const int* __restrict__ dstp,
    const __half* __restrict__ Ah, const __half* __restrict__ Bh,
    const float* __restrict__ Cw, const float* __restrict__ Cb,
    __half* __restrict__ enh, float* __restrict__ partial, int E)
{
    __shared__ float red[256];
    int tid = threadIdx.x;
    int lane = tid & 63;
    int m = lane & 15, q = lane >> 4;
    half8_t b0, b1;
#pragma unroll
    for (int i = 0; i < 8; i++) {
        int k = q * 8 + i;
        b0[i] = (_Float16)Cw[k * 32 + m];
        b1[i] = (_Float16)Cw[k * 32 + m + 16];
    }
    float cb0 = Cb[m], cb1 = Cb[m + 16];
    float es0 = 0.f, eq0 = 0.f, es1 = 0.f, eq1 = 0.f;

    int ntile = (E + 15) >> 4;
    int wid = blockIdx.x * 4 + (tid >> 6);
    int nwave = gridDim.x * 4;
    for (int t = wid; t < ntile; t += nwave) {
        int base = t << 4;
        int arow = base + m;
        if (arow >= E) arow = E - 1;
        half8_t a = *(const half8_t*)(ep + (size_t)arow * 32 + q * 8);
        float4_t acc0 = __builtin_amdgcn_mfma_f32_16x16x32_f16(a, b0, (float4_t){0.f,0.f,0.f,0.f}, 0, 0, 0);
        float4_t acc1 = __builtin_amdgcn_mfma_f32_16x16x32_f16(a, b1, (float4_t){0.f,0.f,0.f,0.f}, 0, 0, 0);
#pragma unroll
        for (int reg = 0; reg < 4; reg++) {
            int row = q * 4 + reg;
            int edge = base + row;
            if (edge < E) {
                int s = srcp[edge], d = dstp[edge];
                float ah0 = __half2float(Ah[(size_t)d * 32 + m]);
                float bh0 = __half2float(Bh[(size_t)s * 32 + m]);
                float ah1 = __half2float(Ah[(size_t)d * 32 + m + 16]);
                float bh1 = __half2float(Bh[(size_t)s * 32 + m + 16]);
                float en0 = acc0[reg] + cb0 + ah0 + bh0;
                float en1 = acc1[reg] + cb1 + ah1 + bh1;
                enh[(size_t)edge * 32 + m]      = __float2half_rn(en0);
                enh[(size_t)edge * 32 + m + 16] = __float2half_rn(en1);
                es0 += en0; eq0 += en0 * en0;
                es1 += en1; eq1 += en1 * en1;
            }
        }
    }
    float* p = partial + (size_t)blockIdx.x * 64;
    __syncthreads();
    red[tid] = es0;
    __syncthreads();
    if (tid < 16) {
        float s = 0.f;
#pragma unroll
        for (int w = 0; w < 4; w++)
#pragma unroll
            for (int k = 0; k < 4; k++) s += red[w * 64 + k * 16 + tid];
        p[tid] = s;
    }
    __syncthreads();
    red[tid] = es1;
    __syncthreads();
    if (tid < 16) {
        float s = 0.f;
#pragma unroll
        for (int w = 0; w < 4; w++)
#pragma unroll
            for (int k = 0; k < 4; k++) s += red[w * 64 + k * 16 + tid];
        p[16 + tid] = s;
    }
    __syncthreads();
    red[tid] = eq0;
    __syncthreads();
    if (tid < 16) {
        float s = 0.f;
#pragma unroll
        for (int w = 0; w < 4; w++)
#pragma unroll
            for (int k = 0; k < 4; k++) s += red[w * 64 + k * 16 + tid];
        p[32 + tid] = s;
    }
    __syncthreads();
    red[tid] = eq1;
    __syncthreads();
    if (tid < 16) {
        float s = 0.f;
#pragma unroll
        for (int w = 0; w < 4; w++)
#pragma unroll
            for (int k = 0; k < 4; k++) s += red[w * 64 + k * 16 + tid];
        p[48 + tid] = s;
    }
}

// ---- phase B: half2 CSR walk; 16 lanes/node, 2 cols/lane; fused e-apply; h-BN partials ----
__global__ __launch_bounds__(256) void node_agg(
    const __half* __restrict__ enh, const int* __restrict__ srcp,
    const int* __restrict__ offsets, const int* __restrict__ counts,
    const __half* __restrict__ Vh, float* __restrict__ hnew,
    __half* __restrict__ ep, const float* __restrict__ sc_e, const float* __restrict__ sh_e,
    float* __restrict__ partial, int N)
{
    __shared__ float red[512];
    int tid = threadIdx.x, u = tid & 15, grp = tid >> 4;   // 16 groups of 16 lanes
    int c0 = 2 * u;
    float sc0 = sc_e[c0], sh0 = sh_e[c0];
    float sc1 = sc_e[c0 + 1], sh1 = sh_e[c0 + 1];
    float hs0 = 0.f, hq0 = 0.f, hs1 = 0.f, hq1 = 0.f;
    for (int nb0 = blockIdx.x * 16; nb0 < N; nb0 += gridDim.x * 16) {
        int node = nb0 + grp;
        if (node >= N) break;
        int start = offsets[node], len = counts[node];
        float num0 = 0.f, den0 = 0.f, num1 = 0.f, den1 = 0.f;
        int qq = 0;
        for (; qq + 2 <= len; qq += 2) {
            int p0 = start + qq, p1 = p0 + 1;
            int s0 = srcp[p0], s1 = srcp[p1];
            float2 en0 = __half22float2(*(const __half2*)(enh + (size_t)p0 * 32 + c0));
            float2 en1 = __half22float2(*(const __half2*)(enh + (size_t)p1 * 32 + c0));
            float2 vh0 = __half22float2(*(const __half2*)(Vh + (size_t)s0 * 32 + c0));
            float2 vh1 = __half22float2(*(const __half2*)(Vh + (size_t)s1 * 32 + c0));
            float2 e0 = __half22float2(*(const __half2*)(ep + (size_t)p0 * 32 + c0));
            float2 e1 = __half22float2(*(const __half2*)(ep + (size_t)p1 * 32 + c0));
            float sg00 = 1.f / (1.f + __expf(-en0.x)), sg01 = 1.f / (1.f + __expf(-en0.y));
            float sg10 = 1.f / (1.f + __expf(-en1.x)), sg11 = 1.f / (1.f + __expf(-en1.y));
            num0 = fmaf(sg00, vh0.x, num0); num1 = fmaf(sg01, vh0.y, num1);
            num0 = fmaf(sg10, vh1.x, num0); num1 = fmaf(sg11, vh1.y, num1);
            den0 += sg00 + sg10; den1 += sg01 + sg11;
            *(__half2*)(ep + (size_t)p0 * 32 + c0) = __floats2half2_rn(
                e0.x + fmaxf(fmaf(en0.x, sc0, sh0), 0.f),
                e0.y + fmaxf(fmaf(en0.y, sc1, sh1), 0.f));
            *(__half2*)(ep + (size_t)p1 * 32 + c0) = __floats2half2_rn(
                e1.x + fmaxf(fmaf(en1.x, sc0, sh0), 0.f),
                e1.y + fmaxf(fmaf(en1.y, sc1, sh1), 0.f));
        }
        if (qq < len) {
            int p0 = start + qq;
            int s0 = srcp[p0];
            float2 en0 = __half22float2(*(const __half2*)(enh + (size_t)p0 * 32 + c0));
            float2 vh0 = __half22float2(*(const __half2*)(Vh + (size_t)s0 * 32 + c0));
            float2 e0 = __half22float2(*(const __half2*)(ep + (size_t)p0 * 32 + c0));
            float sg00 = 1.f / (1.f + __expf(-en0.x)), sg01 = 1.f / (1.f + __expf(-en0.y));
            num0 = fmaf(sg00, vh0.x, num0); num1 = fmaf(sg01, vh0.y, num1);
            den0 += sg00; den1 += sg01;
            *(__half2*)(ep + (size_t)p0 * 32 + c0) = __floats2half2_rn(
                e0.x + fmaxf(fmaf(en0.x, sc0, sh0), 0.f),
                e0.y + fmaxf(fmaf(en0.y, sc1, sh1), 0.f));
        }
        size_t ho = (size_t)node * 32 + c0;
        float hv0 = hnew[ho]     + num0 / (den0 + 1e-6f);   // hnew holds Uh
        float hv1 = hnew[ho + 1] + num1 / (den1 + 1e-6f);
        *(float2*)(hnew + ho) = make_float2(hv0, hv1);
        hs0 += hv0; hq0 += hv0 * hv0;
        hs1 += hv1; hq1 += hv1 * hv1;
    }
    __syncthreads();
    red[tid] = hs0; red[256 + tid] = hs1;
    __syncthreads();
    float* p = partial + (size_t)blockIdx.x * 64;
    if (tid < 32) {
        int uu = tid >> 1, par = tid & 1;
        const float* r = red + par * 256;
        float s = 0.f;
#pragma unroll
        for (int g = 0; g < 16; g++) s += r[g * 16 + uu];
        p[tid] = s;
    }
    __syncthreads();
    red[tid] = hq0; red[256 + tid] = hq1;
    __syncthreads();
    if (tid < 32) {
        int uu = tid >> 1, par = tid & 1;
        const float* r = red + par * 256;
        float s = 0.f;
#pragma unroll
        for (int g = 0; g < 16; g++) s += r[g * 16 + uu];
        p[32 + tid] = s;
    }
}

// ---------------- finalize BN stats for one side: 32 blocks, one per feature ----------------
__global__ __launch_bounds__(256) void stats_side(
    const float* __restrict__ partial, int nrows, double cnt,
    const float* __restrict__ g, const float* __restrict__ b,
    float* __restrict__ sc_out, float* __restrict__ sh_out)
{
    int j = blockIdx.x;
    __shared__ double rs[256], rq[256];
    double s = 0.0, q = 0.0;
    for (int r = threadIdx.x; r < nrows; r += 256) {
        s += (double)partial[(size_t)r * 64 + j];
        q += (double)partial[(size_t)r * 64 + 32 + j];
    }
    rs[threadIdx.x] = s; rq[threadIdx.x] = q;
    __syncthreads();
    for (int off = 128; off; off >>= 1) {
        if (threadIdx.x < off) { rs[threadIdx.x] += rs[threadIdx.x + off]; rq[threadIdx.x] += rq[threadIdx.x + off]; }
        __syncthreads();
    }
    if (threadIdx.x == 0) {
        double mean = rs[0] / cnt;
        double var = rq[0] / cnt - mean * mean;
        float scale = g[j] * (float)(1.0 / sqrt(var + 1e-5));
        sc_out[j] = scale;
        sh_out[j] = b[j] - (float)mean * scale;
    }
}

// ---- final h apply: h16 = fp16(h + relu(hnew*sc+sh)) into a separate buffer ----
__global__ void apply4_h16(const float4* __restrict__ pre, const float* __restrict__ scale,
                           const float* __restrict__ shift, const float4* __restrict__ hold,
                           __half2* __restrict__ h16, size_t n4)
{
    size_t i = (size_t)blockIdx.x * 256 + threadIdx.x;
    if (i < n4) {
        int j4 = (int)(i & 7) * 4;
        float4 sc = *(const float4*)(scale + j4);
        float4 sh = *(const float4*)(shift + j4);
        float4 p = pre[i], a = hold[i];
        a.x += fmaxf(fmaf(p.x, sc.x, sh.x), 0.f);
        a.y += fmaxf(fmaf(p.y, sc.y, sh.y), 0.f);
        a.z += fmaxf(fmaf(p.z, sc.z, sh.z), 0.f);
        a.w += fmaxf(fmaf(p.w, sc.w, sh.w), 0.f);
        h16[i * 2]     = __floats2half2_rn(a.x, a.y);
        h16[i * 2 + 1] = __floats2half2_rn(a.z, a.w);
    }
}

// ---- predictor (MFMA), original edge order: e row via pos[] gather, coalesced out ----
__global__ __launch_bounds__(256) void predictor(
    const __half* __restrict__ h16, const __half* __restrict__ e16,
    const int* __restrict__ srcs, const int* __restrict__ dsts, const int* __restrict__ pos,
    const float* __restrict__ W1, const float* __restrict__ b1,
    const float* __restrict__ W2, const float* __restrict__ b2v,
    float* __restrict__ out, int E)
{
    int tid = threadIdx.x;
    int lane = tid & 63;
    int m = lane & 15, q = lane >> 4;
    half8_t bf00, bf01, bf10, bf11, bf20, bf21;
#pragma unroll
    for (int i = 0; i < 8; i++) {
        int k = q * 8 + i;
        bf00[i] = (_Float16)W1[k * 32 + m];
        bf01[i] = (_Float16)W1[k * 32 + m + 16];
        bf10[i] = (_Float16)W1[(32 + k) * 32 + m];
        bf11[i] = (_Float16)W1[(32 + k) * 32 + m + 16];
        bf20[i] = (_Float16)W1[(64 + k) * 32 + m];
        bf21[i] = (_Float16)W1[(64 + k) * 32 + m + 16];
    }
    float b10 = b1[m], b11 = b1[m + 16];
    float w20 = W2[m], w21 = W2[m + 16];
    float b2 = b2v[0];

    int ntile = (E + 15) >> 4;
    int wid = blockIdx.x * 4 + (tid >> 6);
    int nwave = gridDim.x * 4;
    for (int t = wid; t < ntile; t += nwave) {
        int base = t << 4;
        int arow = base + m;
        if (arow >= E) arow = E - 1;
        int s = srcs[arow], d = dsts[arow];
        int erow = pos[arow];
        half8_t a0 = *(const half8_t*)(h16 + (size_t)s * 32 + q * 8);
        half8_t a1 = *(const half8_t*)(h16 + (size_t)d * 32 + q * 8);
        half8_t a2 = *(const half8_t*)(e16 + (size_t)erow * 32 + q * 8);
        float4_t acc0 = {0.f, 0.f, 0.f, 0.f}, acc1 = {0.f, 0.f, 0.f, 0.f};
        acc0 = __builtin_amdgcn_mfma_f32_16x16x32_f16(a0, bf00, acc0, 0, 0, 0);
        acc1 = __builtin_amdgcn_mfma_f32_16x16x32_f16(a0, bf01, acc1, 0, 0, 0);
        acc0 = __builtin_amdgcn_mfma_f32_16x16x32_f16(a1, bf10, acc0, 0, 0, 0);
        acc1 = __builtin_amdgcn_mfma_f32_16x16x32_f16(a1, bf11, acc1, 0, 0, 0);
        acc0 = __builtin_amdgcn_mfma_f32_16x16x32_f16(a2, bf20, acc0, 0, 0, 0);
        acc1 = __builtin_amdgcn_mfma_f32_16x16x32_f16(a2, bf21, acc1, 0, 0, 0);
#pragma unroll
        for (int reg = 0; reg < 4; reg++) {
            float tp = fmaxf(acc0[reg] + b10, 0.f) * w20
                     + fmaxf(acc1[reg] + b11, 0.f) * w21;
            tp += __shfl_xor(tp, 1);
            tp += __shfl_xor(tp, 2);
            tp += __shfl_xor(tp, 4);
            tp += __shfl_xor(tp, 8);
            int edge = base + q * 4 + reg;
            if (m == 0 && edge < E) out[edge] = tp + b2;
        }
    }
}

extern "C" void kernel_launch(void* const* d_in, const int* in_sizes, int n_in,
                              void* d_out, int out_size, void* d_ws, size_t ws_size,
                              hipStream_t stream)
{
    const int N = in_sizes[0];
    const int E = in_sizes[1];

    const float* x    = (const float*)d_in[0];
    const float* e_in = (const float*)d_in[1];
    const int*   eidx = (const int*)d_in[2];
    const float* pe_w = (const float*)d_in[3];
    const float* pe_b = (const float*)d_in[4];
    const float* ed_w = (const float*)d_in[5];
    const float* ed_b = (const float*)d_in[6];
    const float* Aw = (const float*)d_in[7];
    const float* Ab = (const float*)d_in[8];
    const float* Bw = (const float*)d_in[9];
    const float* Bb = (const float*)d_in[10];
    const float* Cw = (const float*)d_in[11];
    const float* Cb = (const float*)d_in[12];
    const float* Uw = (const float*)d_in[13];
    const float* Ub = (const float*)d_in[14];
    const float* Vw = (const float*)d_in[15];
    const float* Vb = (const float*)d_in[16];
    const float* bn_h_g = (const float*)d_in[17];
    const float* bn_h_b = (const float*)d_in[18];
    const float* bn_e_g = (const float*)d_in[19];
    const float* bn_e_b = (const float*)d_in[20];
    const float* W1w = (const float*)d_in[21];
    const float* W1b = (const float*)d_in[22];
    const float* W2w = (const float*)d_in[23];
    const float* W2b = (const float*)d_in[24];

    const int* srcs = eidx;
    const int* dsts = eidx + E;

    size_t nh = (size_t)N * 32;
    size_t eh = (size_t)E * 32;

    float* ws = (float*)d_ws;
    float* stats     = ws;                            // 128
    float* partial_h = stats + 128;                   // GRID_STRIDE*64
    float* partial_e = partial_h + GRID_STRIDE * 64;  // GRID_STRIDE*64
    float* h    = partial_e + GRID_STRIDE * 64;       // nh floats
    float* hnew = h + nh;                             // nh floats (Uh then h_new)
    __half* Ah  = (__half*)(hnew + nh);               // nh halves (h16 at the end)
    __half* Bh  = Ah + nh;                            // nh halves
    __half* Vh  = Bh + nh;                            // nh halves
    __half* ep  = Vh + nh;                            // eh halves (final e16 at the end)
    __half* enh = ep + eh;                            // eh halves
    int* counts    = (int*)(enh + eh);
    int* offsets   = counts + N;
    int* cursor    = offsets + N;
    int* blocksums = cursor + N;   // 128
    int* perm      = blocksums + 128;
    int* srcp      = perm + E;
    int* dstp      = srcp + E;
    int* pos       = dstp + E;

    size_t nh4 = nh / 4, eh4 = eh / 4;
    int gh4 = (int)((nh4 + 255) / 256);
    int ge4 = (int)((eh4 + 255) / 256);
    int gN = (N + 255) / 256;
    int gE = (E + 255) / 256;
    int nb = (N + 1023) / 1024;
    int ntileN = (N + 15) / 16;
    int gGemm = (ntileN + 3) / 4;
    if (gGemm > GRID_STRIDE) gGemm = GRID_STRIDE;

    // ---- CSR build (dst-sorted edge permutation) ----
    zero_ints<<<gN, 256, 0, stream>>>(counts, N);
    hist_kernel<<<gE, 256, 0, stream>>>(dsts, counts, E);
    scan1<<<nb, 256, 0, stream>>>(counts, offsets, blocksums, N);
    scan2<<<1, 64, 0, stream>>>(blocksums, nb);
    scan3<<<gN, 256, 0, stream>>>(offsets, blocksums, cursor, N);
    scatter_perm<<<GRID_STRIDE, 256, 0, stream>>>(dsts, cursor, perm, pos, E, N);
    gather_sd<<<gE, 256, 0, stream>>>(perm, srcs, dsts, srcp, dstp, E);

    // ---- input projections ----
    init_proj4<<<gh4, 256, 0, stream>>>(x, pe_w, pe_b, (float4*)h, nh4);
    init_ep16<<<ge4, 256, 0, stream>>>(e_in, perm, ed_w, ed_b, (__half2*)ep, eh4);

    for (int l = 0; l < NLAYERS; l++) {
        if (l == 0)
            node_gemm<0><<<gGemm, 256, 0, stream>>>(h, hnew, stats + 0, stats + 32,
                Aw + l * 1024, Ab + l * 32, Bw + l * 1024, Bb + l * 32,
                Uw + l * 1024, Ub + l * 32, Vw + l * 1024, Vb + l * 32,
                Ah, Bh, hnew, Vh, N);
        else
            node_gemm<1><<<gGemm, 256, 0, stream>>>(h, hnew, stats + 0, stats + 32,
                Aw + l * 1024, Ab + l * 32, Bw + l * 1024, Bb + l * 32,
                Uw + l * 1024, Ub + l * 32, Vw + l * 1024, Vb + l * 32,
                Ah, Bh, hnew, Vh, N);
        edge_en<<<GRID_STRIDE, 256, 0, stream>>>(ep, srcp, dstp, Ah, Bh,
            Cw + l * 1024, Cb + l * 32, enh, partial_e, E);
        stats_side<<<32, 256, 0, stream>>>(partial_e, GRID_STRIDE, (double)E,
            bn_e_g + l * 32, bn_e_b + l * 32, stats + 64, stats + 96);
        node_agg<<<GRID_STRIDE, 256, 0, stream>>>(enh, srcp, offsets, counts,
            Vh, hnew, ep, stats + 64, stats + 96, partial_h, N);
        stats_side<<<32, 256, 0, stream>>>(partial_h, GRID_STRIDE, (double)N,
            bn_h_g + l * 32, bn_h_b + l * 32, stats + 0, stats + 32);
    }

    // final h-update straight to fp16 (Ah already consumed by edge_en l=3)
    apply4_h16<<<gh4, 256, 0, stream>>>((const float4*)hnew, stats + 0, stats + 32,
                                        (const float4*)h, (__half2*)Ah, nh4);

    predictor<<<GRID_STRIDE, 256, 0, stream>>>((const __half*)Ah, (const __half*)ep,
                                               srcs, dsts, pos, W1w, W1b, W2w, W2b,
                                               (float*)d_out, E);
}